// Round 4
// baseline (454.610 us; speedup 1.0000x reference)
//
#include <hip/hip_runtime.h>
#include <hip/hip_cooperative_groups.h>
#include <cstdint>
#include <cstddef>

namespace cg = cooperative_groups;

#define B_   4
#define S_   2047
#define T_   2048
#define D_   256
#define H_   8
#define DK_  32
#define DFF_ 512
#define L_   2

typedef short          s8v  __attribute__((ext_vector_type(8)));
typedef float          f4v  __attribute__((ext_vector_type(4)));
typedef unsigned short u8v  __attribute__((ext_vector_type(8)));
typedef unsigned int   u2v  __attribute__((ext_vector_type(2)));
typedef unsigned int   uint32;

union U8 { u8v v; unsigned short e[8]; };

__device__ __forceinline__ float bf2f(unsigned short h) {
    unsigned int u = ((unsigned int)h) << 16;
    float f; __builtin_memcpy(&f, &u, 4); return f;
}
__device__ __forceinline__ unsigned short f2bf(float f) {
    unsigned int u; __builtin_memcpy(&u, &f, 4);
    u += 0x7fffu + ((u >> 16) & 1u);        // RNE
    return (unsigned short)(u >> 16);
}
__device__ __forceinline__ uint32 pack_bf2(float lo, float hi) {
    uint32 a, b;
    __builtin_memcpy(&a, &lo, 4); __builtin_memcpy(&b, &hi, 4);
    a += 0x8000u; b += 0x8000u;
    return __builtin_amdgcn_perm(b, a, 0x07060302);  // hi16(b)<<16 | hi16(a)
}

// log2(e)/sqrt(32): Q pre-scale so softmax runs in base-2 (exp2 = bare v_exp_f32)
#define QSCALE2 0.25503485951542068f

// ------- prep: embed (blocks 0..1023) + ALL weight transposes (1024..2047) --
__global__ __launch_bounds__(256) void prep_k(
    const float* __restrict__ emb, const int* __restrict__ toks,
    const float* __restrict__ tokE, const float* __restrict__ pe,
    unsigned short* __restrict__ X,
    const float* __restrict__ Wq, const float* __restrict__ Wk,
    const float* __restrict__ Wv, const float* __restrict__ Wo,
    const float* __restrict__ W1, const float* __restrict__ W2,
    unsigned short* __restrict__ WqkvT, unsigned short* __restrict__ WoT,
    unsigned short* __restrict__ W1T, unsigned short* __restrict__ W2T)
{
    __shared__ float tile[32][33];
    if (blockIdx.x < 1024) {
        int idx = blockIdx.x * 256 + threadIdx.x;      // B*T*32
        int d8 = (idx & 31) * 8;
        int t  = (idx >> 5) & (T_ - 1);
        int b  = idx >> 16;
        const float* src = (t == 0) ? (emb + b * D_)
                                    : (tokE + (size_t)toks[b * S_ + t - 1] * D_);
        const float* p = pe + (size_t)t * D_ + d8;
        U8 o;
#pragma unroll
        for (int j = 0; j < 8; ++j) o.e[j] = f2bf(src[d8 + j] + p[j]);
        *(u8v*)(X + (size_t)(b * T_ + t) * D_ + d8) = o.v;
        return;
    }
    int idx = blockIdx.x - 1024;
    const float* src; unsigned short* dst; int R, C, tr, tc;
    if (idx < 512) {
        int w = idx >> 7, rem = idx & 127, l = rem >> 6, t = rem & 63;
        tr = t >> 3; tc = t & 7; R = 256; C = 256;
        src = (w == 0 ? Wq : w == 1 ? Wk : w == 2 ? Wv : Wo) + (size_t)l * 65536;
        dst = (w < 3) ? WqkvT + (size_t)l * 196608 + (size_t)w * 65536
                      : WoT + (size_t)l * 65536;
    } else if (idx < 768) {
        int rem = idx - 512, l = rem >> 7, t = rem & 127;
        tr = t >> 4; tc = t & 15; R = 256; C = 512;
        src = W1 + (size_t)l * 131072; dst = W1T + (size_t)l * 131072;
    } else {
        int rem = idx - 768, l = rem >> 7, t = rem & 127;
        tr = t >> 3; tc = t & 7; R = 512; C = 256;
        src = W2 + (size_t)l * 131072; dst = W2T + (size_t)l * 131072;
    }
    int x = threadIdx.x & 31, y = threadIdx.x >> 5;
    int r0 = tr * 32, c0 = tc * 32;
#pragma unroll
    for (int i = 0; i < 32; i += 8) tile[y + i][x] = src[(size_t)(r0 + y + i) * C + c0 + x];
    __syncthreads();
#pragma unroll
    for (int i = 0; i < 32; i += 8)
        dst[(size_t)(c0 + y + i) * R + r0 + x] = f2bf(tile[x][y + i]);
}

// ---------------------------------------------------------------------------
// One cooperative kernel for BOTH layers.  256 blocks x 512 threads, 1/CU.
// Per layer: phase1 QKV (two 4-wave groups x 3 tiles each) -> grid.sync ->
// phase2 flash-attn (one 128-row q-tile pair per block, 17 k-iters const) ->
// grid.sync -> phase3 tail (U1+LN1, FF1, U2+LN2, BK=32, all row-local in LDS).
// Max LDS over phases = 57856 B (tail) < 64 KB static.
// ---------------------------------------------------------------------------
struct LArgs {
    const unsigned short *WqkvT, *WoT, *W1T, *W2T;
    const float *bo, *g1, *be1, *b1, *b2, *g2, *be2;
    unsigned short *Xa, *Qh, *Kh, *VT, *AO;
    float *out;
};

__global__ __launch_bounds__(512, 2) void layers_k(LArgs A)
{
    __shared__ unsigned short SM[28928];   // 57856 B
    cg::grid_group grid = cg::this_grid();

    const int tid = threadIdx.x;
    const int wave = tid >> 6, lane = tid & 63, l15 = lane & 15, quad = lane >> 4;
    const int bx = blockIdx.x;

    for (int l = 0; l < L_; ++l) {
        // ==================== phase 1: QKV projection ====================
        {
            const unsigned short* WqkvTl = A.WqkvT + (size_t)l * 3 * D_ * D_;
            const int g = tid >> 8, ltid = tid & 255;   // two 4-wave groups
            const int wl = wave & 3;
            unsigned short* At = SM + g * 9216;          // 64*72
            unsigned short* Wt = At + 4608;
            const int arow = ltid >> 2, acg = (ltid & 3) * 16;
            for (int u = 0; u < 3; ++u) {
                const int idx = u * 512 + bx * 2 + g;    // pairs share same y
                const int y = idx >> 7, m0 = (idx & 127) * 64;
                const unsigned short* ag = A.Xa + (size_t)(m0 + arow) * D_ + acg;
                const unsigned short* wg = WqkvTl + (size_t)(y * 64 + arow) * D_ + acg;
                u8v a0 = *(const u8v*)ag, a1 = *(const u8v*)(ag + 8);
                u8v w0 = *(const u8v*)wg, w1 = *(const u8v*)(wg + 8);
                f4v acc[4];
#pragma unroll
                for (int i = 0; i < 4; ++i) acc[i] = (f4v){0.f, 0.f, 0.f, 0.f};
#pragma unroll
                for (int kk = 0; kk < 4; ++kk) {
                    *(u8v*)&At[arow * 72 + acg] = a0; *(u8v*)&At[arow * 72 + acg + 8] = a1;
                    *(u8v*)&Wt[arow * 72 + acg] = w0; *(u8v*)&Wt[arow * 72 + acg + 8] = w1;
                    __syncthreads();
                    if (kk < 3) {
                        int o = (kk + 1) * 64;
                        a0 = *(const u8v*)(ag + o); a1 = *(const u8v*)(ag + o + 8);
                        w0 = *(const u8v*)(wg + o); w1 = *(const u8v*)(wg + o + 8);
                    }
#pragma unroll
                    for (int ks = 0; ks < 2; ++ks) {
                        s8v aF = *(const s8v*)&At[(wl * 16 + l15) * 72 + ks * 32 + quad * 8];
#pragma unroll
                        for (int nt = 0; nt < 4; ++nt) {
                            s8v wF = *(const s8v*)&Wt[(nt * 16 + l15) * 72 + ks * 32 + quad * 8];
                            acc[nt] = __builtin_amdgcn_mfma_f32_16x16x32_bf16(aF, wF, acc[nt], 0, 0, 0);
                        }
                    }
                    __syncthreads();
                }
                const int b = m0 >> 11, t0 = m0 & (T_ - 1);
                const int sub = y >> 2, cb = (y & 3) * 64;
                if (sub < 2) {
                    unsigned short* dst = sub ? A.Kh : A.Qh;
                    float sc = sub ? 1.f : QSCALE2;
#pragma unroll
                    for (int nt = 0; nt < 4; ++nt) {
                        int c = cb + nt * 16 + l15, hh = c >> 5, dk = c & 31;
#pragma unroll
                        for (int r = 0; r < 4; ++r) {
                            int t = t0 + wl * 16 + quad * 4 + r;
                            dst[((size_t)(b * H_ + hh) * T_ + t) * DK_ + dk] = f2bf(acc[nt][r] * sc);
                        }
                    }
                } else {
                    unsigned short* Vb = At;   // group-local scratch [64][72]
#pragma unroll
                    for (int nt = 0; nt < 4; ++nt) {
                        int base = (nt * 16 + l15) * 72 + wl * 16 + quad * 4;
                        *(uint32*)&Vb[base]     = pack_bf2(acc[nt][0], acc[nt][1]);
                        *(uint32*)&Vb[base + 2] = pack_bf2(acc[nt][2], acc[nt][3]);
                    }
                }
                __syncthreads();               // symmetric in both groups
                if (sub == 2) {
                    unsigned short* Vb = At;
                    int c = ltid >> 2, chunk = ltid & 3;
                    int cg2 = cb + c, hh = cg2 >> 5, dk = cg2 & 31;
                    unsigned short* dst = A.VT + ((size_t)(b * H_ + hh) * DK_ + dk) * T_ + t0 + chunk * 16;
                    u8v v0 = *(u8v*)&Vb[c * 72 + chunk * 16];
                    u8v v1 = *(u8v*)&Vb[c * 72 + chunk * 16 + 8];
                    *(u8v*)dst = v0; *(u8v*)(dst + 8) = v1;
                }
                __syncthreads();               // protect Vb before next staging
            }
        }
        grid.sync();

        // ==================== phase 2: flash attention ====================
        {
            unsigned short* Kt = SM;                     // 128 x 40
            unsigned short* Vt = SM + 5120;              // 32 x 152
            unsigned short* Pw = SM + 9984 + wave * 2176;// per-wave 16 x 136
            const int bh = bx & 31, qp = bx >> 5;
            const int b = bh >> 3, h = bh & 7;
            const size_t hoff = (size_t)bh * T_ * DK_;
            const int krow = tid >> 2, kcol = (tid & 3) * 8;
            const int vdk = tid >> 4, vc = (tid & 15) * 8;
            const unsigned short* kgp = A.Kh + hoff + (size_t)krow * DK_ + kcol;
            const unsigned short* vgp = A.VT + ((size_t)bh * DK_ + vdk) * T_ + vc;
#pragma unroll
            for (int pu = 0; pu < 2; ++pu) {
                const int qt = pu ? 15 - qp : qp;        // pair sums to 17 iters
                const int nkt = qt + 1;
                const int q0w = qt * 128 + wave * 16;
                s8v qB = *(const s8v*)(A.Qh + hoff + (size_t)(q0w + l15) * DK_ + quad * 8);
                f4v O0 = {0,0,0,0}, O1 = {0,0,0,0};
                float l_i = 0.f;
                u8v kr = *(const u8v*)kgp;
                u8v vr = *(const u8v*)vgp;
                for (int kt = 0; kt < nkt; ++kt) {
                    *(u8v*)&Kt[krow * 40 + kcol] = kr;
                    *(u8v*)&Vt[vdk * 152 + vc]   = vr;
                    __syncthreads();
                    if (kt + 1 < nkt) {
                        kr = *(const u8v*)(kgp + (size_t)(kt + 1) * 128 * DK_);
                        vr = *(const u8v*)(vgp + (kt + 1) * 128);
                    }
                    f4v s[8];
                    f4v zero = {0,0,0,0};
#pragma unroll
                    for (int nt = 0; nt < 8; ++nt) {
                        s8v kA = *(const s8v*)&Kt[(nt * 16 + l15) * 40 + quad * 8];
                        s[nt] = __builtin_amdgcn_mfma_f32_16x16x32_bf16(kA, qB, zero, 0, 0, 0);
                    }
                    if (kt == nkt - 1) {
                        int query = q0w + l15;
#pragma unroll
                        for (int nt = 0; nt < 8; ++nt)
#pragma unroll
                            for (int r = 0; r < 4; ++r) {
                                int key = kt * 128 + nt * 16 + quad * 4 + r;
                                if (key > query) s[nt][r] = -1e30f;
                            }
                    }
                    float rs = 0.f;
#pragma unroll
                    for (int nt = 0; nt < 8; ++nt)
#pragma unroll
                        for (int r = 0; r < 4; ++r) {
                            float p = exp2f(s[nt][r]);
                            s[nt][r] = p;
                            rs += p;
                        }
                    rs += __shfl_xor(rs, 16);
                    rs += __shfl_xor(rs, 32);
                    l_i += rs;
#pragma unroll
                    for (int nt = 0; nt < 8; ++nt) {
                        u2v pw;
                        pw.x = pack_bf2(s[nt][0], s[nt][1]);
                        pw.y = pack_bf2(s[nt][2], s[nt][3]);
                        *(u2v*)&Pw[l15 * 136 + nt * 16 + quad * 4] = pw;
                    }
#pragma unroll
                    for (int ks = 0; ks < 4; ++ks) {
                        s8v aP = *(const s8v*)&Pw[l15 * 136 + ks * 32 + quad * 8];
                        s8v v0 = *(const s8v*)&Vt[l15 * 152 + ks * 32 + quad * 8];
                        s8v v1 = *(const s8v*)&Vt[(16 + l15) * 152 + ks * 32 + quad * 8];
                        O0 = __builtin_amdgcn_mfma_f32_16x16x32_bf16(aP, v0, O0, 0, 0, 0);
                        O1 = __builtin_amdgcn_mfma_f32_16x16x32_bf16(aP, v1, O1, 0, 0, 0);
                    }
                    __syncthreads();           // single K/V buffer
                }
#pragma unroll
                for (int r = 0; r < 4; ++r) {
                    float linv = 1.f / __shfl(l_i, quad * 4 + r);
                    int row = q0w + quad * 4 + r;
                    size_t base = (size_t)(b * T_ + row) * D_ + h * DK_;
                    A.AO[base + l15]      = f2bf(O0[r] * linv);
                    A.AO[base + 16 + l15] = f2bf(O1[r] * linv);
                }
            }
        }
        grid.sync();

        // ==================== phase 3: fused tail (BK=32) ====================
        {
            unsigned short* Wt  = SM;                    // 256 x 40
            unsigned short* As  = SM + 10240;            // 32 x 40
            unsigned short* X1s = SM + 11520;            // 32 x 264
            unsigned short* Hs  = SM + 19968;            // 32 x 264
            float* LNsc = (float*)(SM + 28416);          // 256 f32

            const unsigned short* WoTl = A.WoT + (size_t)l * D_ * D_;
            const unsigned short* W1Tl = A.W1T + (size_t)l * D_ * DFF_;
            const unsigned short* W2Tl = A.W2T + (size_t)l * DFF_ * D_;
            const float* pbo = A.bo + l * D_;
            const float* pg1 = A.g1 + l * D_;  const float* pe1 = A.be1 + l * D_;
            const float* pb1 = A.b1 + l * DFF_;
            const float* pb2 = A.b2 + l * D_;
            const float* pg2 = A.g2 + l * D_;  const float* pe2 = A.be2 + l * D_;

            const int wr = wave >> 2, wc = wave & 3;
            const int m0 = bx * 32;
            const int rbase = wr * 16 + quad * 4;
            const int wrow = tid >> 1, wcol = (tid & 1) * 16;
            const int arow = tid >> 2, acol = (tid & 3) * 8;    // tid < 128

            const unsigned short* wgo  = WoTl + (size_t)wrow * 256 + wcol;
            const unsigned short* wg1  = W1Tl + (size_t)wrow * 256 + wcol;
            const unsigned short* wg1b = wg1 + 256 * 256;
            const unsigned short* wg2  = W2Tl + (size_t)wrow * 512 + wcol;
            const unsigned short* ag   = A.AO + (size_t)(m0 + arow) * D_ + acol;

            f4v accA[4], accU[4];
            u8v w0, w1, a0 = {0,0,0,0,0,0,0,0};

#define TLDW(p, o) { w0 = *(const u8v*)((p) + (o)); w1 = *(const u8v*)((p) + (o) + 8); }
#define TSTW { *(u8v*)&Wt[wrow * 40 + wcol] = w0; *(u8v*)&Wt[wrow * 40 + wcol + 8] = w1; }

            // ---- U1: AO @ WoT^T ----
#pragma unroll
            for (int i = 0; i < 4; ++i) accA[i] = (f4v){0.f, 0.f, 0.f, 0.f};
            TLDW(wgo, 0);
            if (tid < 128) a0 = *(const u8v*)ag;
#pragma unroll
            for (int kk = 0; kk < 8; ++kk) {
                TSTW;
                if (tid < 128) *(u8v*)&As[arow * 40 + acol] = a0;
                __syncthreads();
                if (kk < 7) { TLDW(wgo, (kk + 1) * 32); if (tid < 128) a0 = *(const u8v*)(ag + (kk + 1) * 32); }
                else        { TLDW(wg1, 0); }
                s8v aF = *(const s8v*)&As[(wr * 16 + l15) * 40 + quad * 8];
#pragma unroll
                for (int nt = 0; nt < 4; ++nt) {
                    s8v wF = *(const s8v*)&Wt[(wc * 64 + nt * 16 + l15) * 40 + quad * 8];
                    accA[nt] = __builtin_amdgcn_mfma_f32_16x16x32_bf16(aF, wF, accA[nt], 0, 0, 0);
                }
                __syncthreads();
            }
            // ---- U1 epilogue: bias + resid + LN1 -> X1s ----
            {
                float ps[4] = {0,0,0,0}, pq[4] = {0,0,0,0};
#pragma unroll
                for (int nt = 0; nt < 4; ++nt) {
                    int c = wc * 64 + nt * 16 + l15;
                    float bv = pbo[c];
#pragma unroll
                    for (int r = 0; r < 4; ++r) {
                        float v = accA[nt][r] + bv + bf2f(A.Xa[(size_t)(m0 + rbase + r) * D_ + c]);
                        accA[nt][r] = v; ps[r] += v; pq[r] += v * v;
                    }
                }
#pragma unroll
                for (int r = 0; r < 4; ++r) {
                    float s = ps[r], q = pq[r];
                    s += __shfl_xor(s, 1); q += __shfl_xor(q, 1);
                    s += __shfl_xor(s, 2); q += __shfl_xor(q, 2);
                    s += __shfl_xor(s, 4); q += __shfl_xor(q, 4);
                    s += __shfl_xor(s, 8); q += __shfl_xor(q, 8);
                    if (l15 == 0) { LNsc[(rbase + r) * 4 + wc] = s; LNsc[128 + (rbase + r) * 4 + wc] = q; }
                }
                __syncthreads();
#pragma unroll
                for (int r = 0; r < 4; ++r) {
                    int row = rbase + r;
                    float s = LNsc[row * 4] + LNsc[row * 4 + 1] + LNsc[row * 4 + 2] + LNsc[row * 4 + 3];
                    float q = LNsc[128 + row * 4] + LNsc[128 + row * 4 + 1] + LNsc[128 + row * 4 + 2] + LNsc[128 + row * 4 + 3];
                    float m = s * (1.f / 256.f);
                    float rsg = rsqrtf(q * (1.f / 256.f) - m * m + 1e-5f);
#pragma unroll
                    for (int nt = 0; nt < 4; ++nt) {
                        int c = wc * 64 + nt * 16 + l15;
                        X1s[row * 264 + c] = f2bf((accA[nt][r] - m) * rsg * pg1[c] + pe1[c]);
                    }
                }
                __syncthreads();
            }
            // ---- FF1a: H[:,0:256] ----
#pragma unroll
            for (int i = 0; i < 4; ++i) accA[i] = (f4v){0.f, 0.f, 0.f, 0.f};
#pragma unroll
            for (int kk = 0; kk < 8; ++kk) {
                TSTW;
                __syncthreads();
                if (kk < 7) { TLDW(wg1, (kk + 1) * 32); } else { TLDW(wg2, 0); }
                s8v aF = *(const s8v*)&X1s[(wr * 16 + l15) * 264 + kk * 32 + quad * 8];
#pragma unroll
                for (int nt = 0; nt < 4; ++nt) {
                    s8v wF = *(const s8v*)&Wt[(wc * 64 + nt * 16 + l15) * 40 + quad * 8];
                    accA[nt] = __builtin_amdgcn_mfma_f32_16x16x32_bf16(aF, wF, accA[nt], 0, 0, 0);
                }
                __syncthreads();
            }
#pragma unroll
            for (int nt = 0; nt < 4; ++nt) {
                int c = wc * 64 + nt * 16 + l15;
                float bv = pb1[c];
#pragma unroll
                for (int r = 0; r < 4; ++r) {
                    float v = accA[nt][r] + bv; v = v > 0.f ? v : 0.f;
                    Hs[(rbase + r) * 264 + c] = f2bf(v);
                }
            }
            // ---- U2a: accU += H[:,0:256] @ W2T[:,0:256]^T ----
#pragma unroll
            for (int i = 0; i < 4; ++i) accU[i] = (f4v){0.f, 0.f, 0.f, 0.f};
#pragma unroll
            for (int kk = 0; kk < 8; ++kk) {
                TSTW;
                __syncthreads();
                if (kk < 7) { TLDW(wg2, (kk + 1) * 32); } else { TLDW(wg1b, 0); }
                s8v aF = *(const s8v*)&Hs[(wr * 16 + l15) * 264 + kk * 32 + quad * 8];
#pragma unroll
                for (int nt = 0; nt < 4; ++nt) {
                    s8v wF = *(const s8v*)&Wt[(wc * 64 + nt * 16 + l15) * 40 + quad * 8];
                    accU[nt] = __builtin_amdgcn_mfma_f32_16x16x32_bf16(aF, wF, accU[nt], 0, 0, 0);
                }
                __syncthreads();
            }
            // ---- FF1b: H[:,256:512] ----
#pragma unroll
            for (int i = 0; i < 4; ++i) accA[i] = (f4v){0.f, 0.f, 0.f, 0.f};
#pragma unroll
            for (int kk = 0; kk < 8; ++kk) {
                TSTW;
                __syncthreads();
                if (kk < 7) { TLDW(wg1b, (kk + 1) * 32); } else { TLDW(wg2, 256); }
                s8v aF = *(const s8v*)&X1s[(wr * 16 + l15) * 264 + kk * 32 + quad * 8];
#pragma unroll
                for (int nt = 0; nt < 4; ++nt) {
                    s8v wF = *(const s8v*)&Wt[(wc * 64 + nt * 16 + l15) * 40 + quad * 8];
                    accA[nt] = __builtin_amdgcn_mfma_f32_16x16x32_bf16(aF, wF, accA[nt], 0, 0, 0);
                }
                __syncthreads();
            }
#pragma unroll
            for (int nt = 0; nt < 4; ++nt) {
                int c = wc * 64 + nt * 16 + l15;
                float bv = pb1[256 + c];
#pragma unroll
                for (int r = 0; r < 4; ++r) {
                    float v = accA[nt][r] + bv; v = v > 0.f ? v : 0.f;
                    Hs[(rbase + r) * 264 + c] = f2bf(v);
                }
            }
            // ---- U2b: accU += H[:,256:512] @ W2T[:,256:512]^T ----
#pragma unroll
            for (int kk = 0; kk < 8; ++kk) {
                TSTW;
                __syncthreads();
                if (kk < 7) { TLDW(wg2, 256 + (kk + 1) * 32); }
                s8v aF = *(const s8v*)&Hs[(wr * 16 + l15) * 264 + kk * 32 + quad * 8];
#pragma unroll
                for (int nt = 0; nt < 4; ++nt) {
                    s8v wF = *(const s8v*)&Wt[(wc * 64 + nt * 16 + l15) * 40 + quad * 8];
                    accU[nt] = __builtin_amdgcn_mfma_f32_16x16x32_bf16(aF, wF, accU[nt], 0, 0, 0);
                }
                __syncthreads();
            }
            // ---- U2 epilogue: bias + resid(X1s) + LN2 -> Xa / f32 out ----
            {
                float ps[4] = {0,0,0,0}, pq[4] = {0,0,0,0};
#pragma unroll
                for (int nt = 0; nt < 4; ++nt) {
                    int c = wc * 64 + nt * 16 + l15;
                    float bv = pb2[c];
#pragma unroll
                    for (int r = 0; r < 4; ++r) {
                        float v = accU[nt][r] + bv + bf2f(X1s[(rbase + r) * 264 + c]);
                        accU[nt][r] = v; ps[r] += v; pq[r] += v * v;
                    }
                }
#pragma unroll
                for (int r = 0; r < 4; ++r) {
                    float s = ps[r], q = pq[r];
                    s += __shfl_xor(s, 1); q += __shfl_xor(q, 1);
                    s += __shfl_xor(s, 2); q += __shfl_xor(q, 2);
                    s += __shfl_xor(s, 4); q += __shfl_xor(q, 4);
                    s += __shfl_xor(s, 8); q += __shfl_xor(q, 8);
                    if (l15 == 0) { LNsc[(rbase + r) * 4 + wc] = s; LNsc[128 + (rbase + r) * 4 + wc] = q; }
                }
                __syncthreads();
#pragma unroll
                for (int r = 0; r < 4; ++r) {
                    int row = rbase + r;
                    float s = LNsc[row * 4] + LNsc[row * 4 + 1] + LNsc[row * 4 + 2] + LNsc[row * 4 + 3];
                    float q = LNsc[128 + row * 4] + LNsc[128 + row * 4 + 1] + LNsc[128 + row * 4 + 2] + LNsc[128 + row * 4 + 3];
                    float m = s * (1.f / 256.f);
                    float rsg = rsqrtf(q * (1.f / 256.f) - m * m + 1e-5f);
#pragma unroll
                    for (int nt = 0; nt < 4; ++nt) {
                        int c = wc * 64 + nt * 16 + l15;
                        float val = (accU[nt][r] - m) * rsg * pg2[c] + pe2[c];
                        if (l == 0) {
                            A.Xa[(size_t)(m0 + row) * D_ + c] = f2bf(val);
                        } else {
                            int gr = m0 + row;
                            int t = gr & (T_ - 1), bb = gr >> 11;
                            if (t) A.out[((size_t)bb * S_ + t - 1) * D_ + c] = val;
                        }
                    }
                }
            }
#undef TLDW
#undef TSTW
        }
        if (l + 1 < L_) grid.sync();
    }
}

extern "C" void kernel_launch(void* const* d_in, const int* in_sizes, int n_in,
                              void* d_out, int out_size, void* d_ws, size_t ws_size,
                              hipStream_t stream)
{
    const float* emb  = (const float*)d_in[0];
    const int*   toks = (const int*)d_in[1];
    const float* tokE = (const float*)d_in[4];
    const float* pe   = (const float*)d_in[5];
    const float* Wq   = (const float*)d_in[6];
    const float* Wk   = (const float*)d_in[7];
    const float* Wv   = (const float*)d_in[8];
    const float* Wo   = (const float*)d_in[9];
    const float* bo   = (const float*)d_in[10];
    const float* g1   = (const float*)d_in[11];
    const float* be1  = (const float*)d_in[12];
    const float* W1   = (const float*)d_in[13];
    const float* b1   = (const float*)d_in[14];
    const float* W2   = (const float*)d_in[15];
    const float* b2   = (const float*)d_in[16];
    const float* g2   = (const float*)d_in[17];
    const float* be2  = (const float*)d_in[18];
    float* out = (float*)d_out;

    unsigned short* ws = (unsigned short*)d_ws;
    size_t off = 0;
    const size_t XSZ = (size_t)B_ * T_ * D_;
    unsigned short* Xa    = ws + off; off += XSZ;
    unsigned short* Xb    = ws + off; off += XSZ;   // unused (layout stability)
    unsigned short* Qh    = ws + off; off += XSZ;
    unsigned short* Kh    = ws + off; off += XSZ;
    unsigned short* VTb   = ws + off; off += XSZ;
    unsigned short* AOb   = ws + off; off += XSZ;
    unsigned short* Hb    = ws + off; off += (size_t)B_ * T_ * DFF_;  // unused
    unsigned short* WqkvT = ws + off; off += (size_t)L_ * 3 * D_ * D_;
    unsigned short* WoT   = ws + off; off += (size_t)L_ * D_ * D_;
    unsigned short* W1T   = ws + off; off += (size_t)L_ * D_ * DFF_;
    unsigned short* W2T   = ws + off; off += (size_t)L_ * DFF_ * D_;
    (void)ws_size; (void)in_sizes; (void)n_in; (void)out_size;
    (void)Xb; (void)Hb;

    prep_k<<<dim3(2048), 256, 0, stream>>>(emb, toks, tokE, pe, Xa,
                                           Wq, Wk, Wv, Wo, W1, W2,
                                           WqkvT, WoT, W1T, W2T);

    LArgs la;
    la.WqkvT = WqkvT; la.WoT = WoT; la.W1T = W1T; la.W2T = W2T;
    la.bo = bo; la.g1 = g1; la.be1 = be1; la.b1 = b1;
    la.b2 = b2; la.g2 = g2; la.be2 = be2;
    la.Xa = Xa; la.Qh = Qh; la.Kh = Kh; la.VT = VTb; la.AO = AOb;
    la.out = out;
    void* kargs[] = { (void*)&la };
    hipLaunchCooperativeKernel((const void*)layers_k, dim3(256), dim3(512),
                               kargs, 0, stream);
}

// Round 5
// 262.725 us; speedup vs baseline: 1.7304x; 1.7304x over previous
//
#include <hip/hip_runtime.h>
#include <cstdint>
#include <cstddef>

#define B_   4
#define S_   2047
#define T_   2048
#define D_   256
#define H_   8
#define DK_  32
#define DFF_ 512
#define L_   2

typedef short          s8v  __attribute__((ext_vector_type(8)));
typedef float          f4v  __attribute__((ext_vector_type(4)));
typedef unsigned short u8v  __attribute__((ext_vector_type(8)));
typedef unsigned int   u2v  __attribute__((ext_vector_type(2)));
typedef unsigned int   uint32;

union U8 { u8v v; unsigned short e[8]; };

__device__ __forceinline__ float bf2f(unsigned short h) {
    unsigned int u = ((unsigned int)h) << 16;
    float f; __builtin_memcpy(&f, &u, 4); return f;
}
__device__ __forceinline__ unsigned short f2bf(float f) {
    unsigned int u; __builtin_memcpy(&u, &f, 4);
    u += 0x7fffu + ((u >> 16) & 1u);        // RNE
    return (unsigned short)(u >> 16);
}
__device__ __forceinline__ uint32 pack_bf2(float lo, float hi) {
    uint32 a, b;
    __builtin_memcpy(&a, &lo, 4); __builtin_memcpy(&b, &hi, 4);
    a += 0x8000u; b += 0x8000u;
    return __builtin_amdgcn_perm(b, a, 0x07060302);  // hi16(b)<<16 | hi16(a)
}

// log2(e)/sqrt(32): Q pre-scale so softmax runs in base-2 (exp2 = bare v_exp_f32)
#define QSCALE2 0.25503485951542068f

// ------- prep: embed (blocks 0..1023) + ALL weight transposes (1024..2047) --
__global__ __launch_bounds__(256) void prep_k(
    const float* __restrict__ emb, const int* __restrict__ toks,
    const float* __restrict__ tokE, const float* __restrict__ pe,
    unsigned short* __restrict__ X,
    const float* __restrict__ Wq, const float* __restrict__ Wk,
    const float* __restrict__ Wv, const float* __restrict__ Wo,
    const float* __restrict__ W1, const float* __restrict__ W2,
    unsigned short* __restrict__ WqkvT, unsigned short* __restrict__ WoT,
    unsigned short* __restrict__ W1T, unsigned short* __restrict__ W2T)
{
    __shared__ float tile[32][33];
    if (blockIdx.x < 1024) {
        int idx = blockIdx.x * 256 + threadIdx.x;      // B*T*32
        int d8 = (idx & 31) * 8;
        int t  = (idx >> 5) & (T_ - 1);
        int b  = idx >> 16;
        const float* src = (t == 0) ? (emb + b * D_)
                                    : (tokE + (size_t)toks[b * S_ + t - 1] * D_);
        const float* p = pe + (size_t)t * D_ + d8;
        U8 o;
#pragma unroll
        for (int j = 0; j < 8; ++j) o.e[j] = f2bf(src[d8 + j] + p[j]);
        *(u8v*)(X + (size_t)(b * T_ + t) * D_ + d8) = o.v;
        return;
    }
    int idx = blockIdx.x - 1024;
    const float* src; unsigned short* dst; int R, C, tr, tc;
    if (idx < 512) {
        int w = idx >> 7, rem = idx & 127, l = rem >> 6, t = rem & 63;
        tr = t >> 3; tc = t & 7; R = 256; C = 256;
        src = (w == 0 ? Wq : w == 1 ? Wk : w == 2 ? Wv : Wo) + (size_t)l * 65536;
        dst = (w < 3) ? WqkvT + (size_t)l * 196608 + (size_t)w * 65536
                      : WoT + (size_t)l * 65536;
    } else if (idx < 768) {
        int rem = idx - 512, l = rem >> 7, t = rem & 127;
        tr = t >> 4; tc = t & 15; R = 256; C = 512;
        src = W1 + (size_t)l * 131072; dst = W1T + (size_t)l * 131072;
    } else {
        int rem = idx - 768, l = rem >> 7, t = rem & 127;
        tr = t >> 3; tc = t & 7; R = 512; C = 256;
        src = W2 + (size_t)l * 131072; dst = W2T + (size_t)l * 131072;
    }
    int x = threadIdx.x & 31, y = threadIdx.x >> 5;
    int r0 = tr * 32, c0 = tc * 32;
#pragma unroll
    for (int i = 0; i < 32; i += 8) tile[y + i][x] = src[(size_t)(r0 + y + i) * C + c0 + x];
    __syncthreads();
#pragma unroll
    for (int i = 0; i < 32; i += 8)
        dst[(size_t)(c0 + y + i) * R + r0 + x] = f2bf(tile[x][y + i]);
}

// ---- GEMM 64x64 tile, BK=64, reg-prefetch.  C = A[M,K] @ WT[N,K]^T ---------
// mode 0: QKV. blockIdx.y in [0,12): sub=y>>2 (0:Q scaled,1:K,2:V transposed)
__global__ __launch_bounds__(256) void gemm64_k(
    const unsigned short* __restrict__ A, const unsigned short* __restrict__ WT,
    const float* __restrict__ bias,
    unsigned short* __restrict__ oq, unsigned short* __restrict__ ok,
    unsigned short* __restrict__ ov, unsigned short* __restrict__ out,
    int K, int Ntot, int mode)
{
    __shared__ unsigned short At[64 * 72];
    __shared__ unsigned short Wt[64 * 72];
    const int tid = threadIdx.x;
    const int wave = tid >> 6, lane = tid & 63, l15 = lane & 15, quad = lane >> 4;
    const int m0 = blockIdx.x * 64, n0g = blockIdx.y * 64;

    f4v acc[4];
#pragma unroll
    for (int i = 0; i < 4; ++i) acc[i] = (f4v){0.f, 0.f, 0.f, 0.f};

    const int arow = tid >> 2, acg = (tid & 3) * 16;
    const unsigned short* ag = A + (size_t)(m0 + arow) * K + acg;
    const unsigned short* wg = WT + (size_t)(n0g + arow) * K + acg;
    u8v a0 = *(const u8v*)ag, a1 = *(const u8v*)(ag + 8);
    u8v w0 = *(const u8v*)wg, w1 = *(const u8v*)(wg + 8);

    const int niter = K >> 6;
    for (int kk = 0; kk < niter; ++kk) {
        *(u8v*)&At[arow * 72 + acg] = a0; *(u8v*)&At[arow * 72 + acg + 8] = a1;
        *(u8v*)&Wt[arow * 72 + acg] = w0; *(u8v*)&Wt[arow * 72 + acg + 8] = w1;
        __syncthreads();
        if (kk + 1 < niter) {
            int o = (kk + 1) * 64;
            a0 = *(const u8v*)(ag + o); a1 = *(const u8v*)(ag + o + 8);
            w0 = *(const u8v*)(wg + o); w1 = *(const u8v*)(wg + o + 8);
        }
#pragma unroll
        for (int ks = 0; ks < 2; ++ks) {
            s8v aF = *(const s8v*)&At[(wave * 16 + l15) * 72 + ks * 32 + quad * 8];
#pragma unroll
            for (int nt = 0; nt < 4; ++nt) {
                s8v wF = *(const s8v*)&Wt[(nt * 16 + l15) * 72 + ks * 32 + quad * 8];
                acc[nt] = __builtin_amdgcn_mfma_f32_16x16x32_bf16(aF, wF, acc[nt], 0, 0, 0);
            }
        }
        __syncthreads();
    }

    const int b = m0 >> 11, t0 = m0 & (T_ - 1);
    if (mode == 0) {
        int sub = blockIdx.y >> 2;
        int cb  = (blockIdx.y & 3) * 64;
        if (sub < 2) {
            unsigned short* dst = sub ? ok : oq;
            float sc = sub ? 1.f : QSCALE2;
#pragma unroll
            for (int nt = 0; nt < 4; ++nt) {
                int c = cb + nt * 16 + l15, hh = c >> 5, dk = c & 31;
#pragma unroll
                for (int r = 0; r < 4; ++r) {
                    int t = t0 + wave * 16 + quad * 4 + r;
                    dst[((size_t)(b * H_ + hh) * T_ + t) * DK_ + dk] = f2bf(acc[nt][r] * sc);
                }
            }
        } else {
            unsigned short* Vb = At;   // reuse: [64 cols][72]
#pragma unroll
            for (int nt = 0; nt < 4; ++nt) {
                int base = (nt * 16 + l15) * 72 + wave * 16 + quad * 4;
                *(uint32*)&Vb[base]     = pack_bf2(acc[nt][0], acc[nt][1]);
                *(uint32*)&Vb[base + 2] = pack_bf2(acc[nt][2], acc[nt][3]);
            }
            __syncthreads();
            int c = tid >> 2, chunk = tid & 3;
            int cg = cb + c, hh = cg >> 5, dk = cg & 31;
            unsigned short* dst = ov + ((size_t)(b * H_ + hh) * DK_ + dk) * T_ + t0 + chunk * 16;
            u8v v0 = *(u8v*)&Vb[c * 72 + chunk * 16];
            u8v v1 = *(u8v*)&Vb[c * 72 + chunk * 16 + 8];
            *(u8v*)dst = v0; *(u8v*)(dst + 8) = v1;
        }
    } else {
#pragma unroll
        for (int nt = 0; nt < 4; ++nt) {
            int c = n0g + nt * 16 + l15;
            float bv = bias[c];
#pragma unroll
            for (int r = 0; r < 4; ++r) {
                float v = acc[nt][r] + bv;
                v = v > 0.f ? v : 0.f;
                out[(size_t)(m0 + wave * 16 + quad * 4 + r) * Ntot + c] = f2bf(v);
            }
        }
    }
}

// ---- fused tail, CONTINUOUS 20-step K-stream, double-buffered W staging, ---
// ---- ONE barrier per step (was 2).  Steps: U1=0..3, FF1a=4..7, FF1b=8..11, -
// ---- U2=12..19.  Epilogues (LN1 / relu / relu / LN2) after steps 3/7/11/19.
// Prefetch: at step g, store step g+1 (regs->LDS buf^1) and issue global load
// of step g+2 -> regs, giving the L2 load ~1.5 steps to land.  8 waves, 1
// block/CU (LDS 134KB) — unchanged occupancy, isolates the pipelining delta.
__global__ __launch_bounds__(512) void tail32_k(
    const unsigned short* __restrict__ AO,
    const unsigned short* __restrict__ WoTl, const float* __restrict__ bo,
    const unsigned short* __restrict__ Xres,   // residual in; bf16 out if !last
    const float* __restrict__ g1, const float* __restrict__ be1,
    const unsigned short* __restrict__ W1Tl, const float* __restrict__ b1,
    const unsigned short* __restrict__ W2Tl, const float* __restrict__ b2,
    const float* __restrict__ g2, const float* __restrict__ be2,
    unsigned short* __restrict__ Xout, float* __restrict__ fout, int last)
{
    __shared__ unsigned short Wt[2][256 * 72];   // 73728 B
    __shared__ unsigned short As[2][32 * 72];    //  9216 B
    __shared__ unsigned short X1s[32 * 264];     // 16896 B (132dw = 4 mod 32)
    __shared__ unsigned short Hs[32 * 520];      // 33280 B (260dw = 4 mod 32)
    __shared__ float LNsc[256];                  //  1024 B

    const int tid = threadIdx.x;
    const int wave = tid >> 6, lane = tid & 63, l15 = lane & 15, quad = lane >> 4;
    const int wr = wave >> 2, wc = wave & 3;
    const int m0 = blockIdx.x * 32;
    const int rbase = wr * 16 + quad * 4;

    const int wrow = tid >> 1, wcol = (tid & 1) * 32;    // W: 256 rows x 64K
    const int arow = tid >> 3, acol = (tid & 7) * 8;     // A: 32 rows x 64K (tid<256)

    const unsigned short* wgo  = WoTl + (size_t)wrow * 256 + wcol;
    const unsigned short* wg1  = W1Tl + (size_t)wrow * 256 + wcol;
    const unsigned short* wg1b = W1Tl + (size_t)(256 + wrow) * 256 + wcol;
    const unsigned short* wg2  = W2Tl + (size_t)wrow * 512 + wcol;
    const unsigned short* ag   = AO + (size_t)(m0 + arow) * 256 + acol;

    f4v acc[4];
    u8v w0, w1, w2, w3, a0 = {0,0,0,0,0,0,0,0};

#define LDW(p, o) { w0 = *(const u8v*)((p)+(o)); w1 = *(const u8v*)((p)+(o)+8); \
                    w2 = *(const u8v*)((p)+(o)+16); w3 = *(const u8v*)((p)+(o)+24); }
#define STW(bf) { *(u8v*)&Wt[bf][wrow*72+wcol] = w0; *(u8v*)&Wt[bf][wrow*72+wcol+8] = w1; \
                  *(u8v*)&Wt[bf][wrow*72+wcol+16] = w2; *(u8v*)&Wt[bf][wrow*72+wcol+24] = w3; }

    // W pointer for stream step g (wave-uniform branches)
    auto wptr = [&](int g) -> const unsigned short* {
        if (g < 4)  return wgo  + g * 64;
        if (g < 8)  return wg1  + (g - 4) * 64;
        if (g < 12) return wg1b + (g - 8) * 64;
        return wg2 + (g - 12) * 64;
    };

    // ---- prolog: stage step 0, load step 1 to regs ----
    LDW(wptr(0), 0);
    if (tid < 256) a0 = *(const u8v*)ag;
    STW(0);
    if (tid < 256) *(u8v*)&As[0][arow * 72 + acol] = a0;
    LDW(wptr(1), 0);
    if (tid < 256) a0 = *(const u8v*)(ag + 64);
    __syncthreads();

#pragma unroll
    for (int i = 0; i < 4; ++i) acc[i] = (f4v){0.f, 0.f, 0.f, 0.f};

    for (int g = 0; g < 20; ++g) {
        const int cur = g & 1, nxt = cur ^ 1;
        if (g == 4 || g == 8 || g == 12) {
#pragma unroll
            for (int i = 0; i < 4; ++i) acc[i] = (f4v){0.f, 0.f, 0.f, 0.f};
        }
        // pipeline: publish step g+1, issue load of step g+2
        if (g + 1 < 20) STW(nxt);
        if (g + 1 < 4 && tid < 256) *(u8v*)&As[nxt][arow * 72 + acol] = a0;
        if (g + 2 < 20) LDW(wptr(g + 2), 0);
        if (g + 2 < 4 && tid < 256) a0 = *(const u8v*)(ag + (g + 2) * 64);

        // MFMA for step g
#pragma unroll
        for (int ks = 0; ks < 2; ++ks) {
            s8v aF;
            if (g < 4)       aF = *(const s8v*)&As[cur][(wr * 16 + l15) * 72 + ks * 32 + quad * 8];
            else if (g < 12) aF = *(const s8v*)&X1s[(wr * 16 + l15) * 264 + ((g - 4) & 3) * 64 + ks * 32 + quad * 8];
            else             aF = *(const s8v*)&Hs[(wr * 16 + l15) * 520 + (g - 12) * 64 + ks * 32 + quad * 8];
#pragma unroll
            for (int nt = 0; nt < 4; ++nt) {
                s8v wF = *(const s8v*)&Wt[cur][(wc * 64 + nt * 16 + l15) * 72 + ks * 32 + quad * 8];
                acc[nt] = __builtin_amdgcn_mfma_f32_16x16x32_bf16(aF, wF, acc[nt], 0, 0, 0);
            }
        }

        // ---- phase epilogues ----
        if (g == 3) {          // U1: bias + resid + LN1 -> X1s
            float ps[4] = {0,0,0,0}, pq[4] = {0,0,0,0};
#pragma unroll
            for (int nt = 0; nt < 4; ++nt) {
                int c = wc * 64 + nt * 16 + l15;
                float bv = bo[c];
#pragma unroll
                for (int r = 0; r < 4; ++r) {
                    float v = acc[nt][r] + bv + bf2f(Xres[(size_t)(m0 + rbase + r) * D_ + c]);
                    acc[nt][r] = v; ps[r] += v; pq[r] += v * v;
                }
            }
#pragma unroll
            for (int r = 0; r < 4; ++r) {
                float s = ps[r], q = pq[r];
                s += __shfl_xor(s, 1); q += __shfl_xor(q, 1);
                s += __shfl_xor(s, 2); q += __shfl_xor(q, 2);
                s += __shfl_xor(s, 4); q += __shfl_xor(q, 4);
                s += __shfl_xor(s, 8); q += __shfl_xor(q, 8);
                if (l15 == 0) { LNsc[(rbase + r) * 4 + wc] = s; LNsc[128 + (rbase + r) * 4 + wc] = q; }
            }
            __syncthreads();
#pragma unroll
            for (int r = 0; r < 4; ++r) {
                int row = rbase + r;
                float s = LNsc[row * 4] + LNsc[row * 4 + 1] + LNsc[row * 4 + 2] + LNsc[row * 4 + 3];
                float q = LNsc[128 + row * 4] + LNsc[128 + row * 4 + 1] + LNsc[128 + row * 4 + 2] + LNsc[128 + row * 4 + 3];
                float m = s * (1.f / 256.f);
                float rsg = rsqrtf(q * (1.f / 256.f) - m * m + 1e-5f);
#pragma unroll
                for (int nt = 0; nt < 4; ++nt) {
                    int c = wc * 64 + nt * 16 + l15;
                    X1s[row * 264 + c] = f2bf((acc[nt][r] - m) * rsg * g1[c] + be1[c]);
                }
            }
        } else if (g == 7) {   // FF1a: relu -> Hs[:,0:256]
#pragma unroll
            for (int nt = 0; nt < 4; ++nt) {
                int c = wc * 64 + nt * 16 + l15;
                float bv = b1[c];
#pragma unroll
                for (int r = 0; r < 4; ++r) {
                    float v = acc[nt][r] + bv; v = v > 0.f ? v : 0.f;
                    Hs[(rbase + r) * 520 + c] = f2bf(v);
                }
            }
        } else if (g == 11) {  // FF1b: relu -> Hs[:,256:512]
#pragma unroll
            for (int nt = 0; nt < 4; ++nt) {
                int c = wc * 64 + nt * 16 + l15;
                float bv = b1[256 + c];
#pragma unroll
                for (int r = 0; r < 4; ++r) {
                    float v = acc[nt][r] + bv; v = v > 0.f ? v : 0.f;
                    Hs[(rbase + r) * 520 + 256 + c] = f2bf(v);
                }
            }
        } else if (g == 19) {  // U2: bias + resid(X1s) + LN2 -> Xout / f32 out
            float ps[4] = {0,0,0,0}, pq[4] = {0,0,0,0};
#pragma unroll
            for (int nt = 0; nt < 4; ++nt) {
                int c = wc * 64 + nt * 16 + l15;
                float bv = b2[c];
#pragma unroll
                for (int r = 0; r < 4; ++r) {
                    float v = acc[nt][r] + bv + bf2f(X1s[(rbase + r) * 264 + c]);
                    acc[nt][r] = v; ps[r] += v; pq[r] += v * v;
                }
            }
#pragma unroll
            for (int r = 0; r < 4; ++r) {
                float s = ps[r], q = pq[r];
                s += __shfl_xor(s, 1); q += __shfl_xor(q, 1);
                s += __shfl_xor(s, 2); q += __shfl_xor(q, 2);
                s += __shfl_xor(s, 4); q += __shfl_xor(q, 4);
                s += __shfl_xor(s, 8); q += __shfl_xor(q, 8);
                if (l15 == 0) { LNsc[(rbase + r) * 4 + wc] = s; LNsc[128 + (rbase + r) * 4 + wc] = q; }
            }
            __syncthreads();
#pragma unroll
            for (int r = 0; r < 4; ++r) {
                int row = rbase + r;
                float s = LNsc[row * 4] + LNsc[row * 4 + 1] + LNsc[row * 4 + 2] + LNsc[row * 4 + 3];
                float q = LNsc[128 + row * 4] + LNsc[128 + row * 4 + 1] + LNsc[128 + row * 4 + 2] + LNsc[128 + row * 4 + 3];
                float m = s * (1.f / 256.f);
                float rsg = rsqrtf(q * (1.f / 256.f) - m * m + 1e-5f);
#pragma unroll
                for (int nt = 0; nt < 4; ++nt) {
                    int c = wc * 64 + nt * 16 + l15;
                    float val = (acc[nt][r] - m) * rsg * g2[c] + be2[c];
                    if (!last) {
                        Xout[(size_t)(m0 + row) * D_ + c] = f2bf(val);
                    } else {
                        int gr = m0 + row;
                        int t = gr & (T_ - 1), bb = gr >> 11;
                        if (t) fout[((size_t)bb * S_ + t - 1) * D_ + c] = val;
                    }
                }
            }
        }
        if (g != 19) __syncthreads();   // single end-of-step barrier
    }
#undef LDW
#undef STW
}

// ---- flash attention, operand-swapped, K/V double-buffered (1 barrier/tile),
// Vt pitch 152 (76dw = 12 mod 32 -> 2-way LDS aliasing, free).
#define KTP 5120   // 128*40 u16 per K buffer
#define VTP 4864   // 32*152 u16 per V buffer
__global__ __launch_bounds__(256) void attn_k(
    const unsigned short* __restrict__ Qh, const unsigned short* __restrict__ Kh,
    const unsigned short* __restrict__ VT, unsigned short* __restrict__ AO)
{
    __shared__ unsigned short Kt[2 * KTP];       // [buf][key][dk] pitch 40
    __shared__ unsigned short Vt[2 * VTP];       // [buf][dk][key] pitch 152
    __shared__ unsigned short Ps[4][16 * 136];   // per-wave P [query][key]

    const int tid = threadIdx.x, wave = tid >> 6, lane = tid & 63;
    const int l15 = lane & 15, quad = lane >> 4;
    const int bh = blockIdx.y, b = bh >> 3, h = bh & 7;
    const size_t hoff = (size_t)bh * T_ * DK_;
    unsigned short* Pw = &Ps[wave][0];

    const int qts[2] = { (int)blockIdx.x, 31 - (int)blockIdx.x };
    const int nk0 = qts[0] / 2 + 1, nk1 = qts[1] / 2 + 1;
    const int ntot = nk0 + nk1;

    const int krow = tid >> 1, khalf = (tid & 1) * 16;
    const int vdk = tid >> 3, vc = (tid & 7) * 16;
    const unsigned short* kgp = Kh + hoff + (size_t)krow * DK_ + khalf;
    const unsigned short* vgp = VT + ((size_t)bh * DK_ + vdk) * T_ + vc;

    u8v kr0 = *(const u8v*)kgp, kr1 = *(const u8v*)(kgp + 8);
    u8v vr0 = *(const u8v*)vgp, vr1 = *(const u8v*)(vgp + 8);

    s8v qB = {0,0,0,0,0,0,0,0};
    f4v O0 = {0,0,0,0}, O1 = {0,0,0,0};
    float l_i = 0.f;
    int nkt = 0, q0w = 0;

    for (int it = 0; it < ntot; ++it) {
        const int phase = (it >= nk0);
        const int kt = phase ? it - nk0 : it;
        unsigned short* Ktb = Kt + (it & 1) * KTP;
        unsigned short* Vtb = Vt + (it & 1) * VTP;
        if (kt == 0) {
            int qt = qts[phase]; nkt = phase ? nk1 : nk0;
            q0w = qt * 64 + wave * 16;
            qB = *(const s8v*)(Qh + hoff + (size_t)(q0w + l15) * DK_ + quad * 8);
            O0 = (f4v){0,0,0,0}; O1 = (f4v){0,0,0,0};
            l_i = 0.f;
        }
        *(u8v*)&Ktb[krow * 40 + khalf]     = kr0;
        *(u8v*)&Ktb[krow * 40 + khalf + 8] = kr1;
        *(u8v*)&Vtb[vdk * 152 + vc]        = vr0;
        *(u8v*)&Vtb[vdk * 152 + vc + 8]    = vr1;
        __syncthreads();    // single barrier/tile (dbuf)
        {
            int itn = it + 1;
            if (itn < ntot) {
                int ktn = (itn >= nk0) ? itn - nk0 : itn;
                const unsigned short* kn = kgp + (size_t)ktn * 128 * DK_;
                const unsigned short* vn = vgp + (size_t)ktn * 128;
                kr0 = *(const u8v*)kn; kr1 = *(const u8v*)(kn + 8);
                vr0 = *(const u8v*)vn; vr1 = *(const u8v*)(vn + 8);
            }
        }
        const int k0 = kt * 128;

        f4v s[8];
        f4v zero = {0,0,0,0};
#pragma unroll
        for (int nt = 0; nt < 8; ++nt) {
            s8v kA = *(const s8v*)&Ktb[(nt * 16 + l15) * 40 + quad * 8];
            s[nt] = __builtin_amdgcn_mfma_f32_16x16x32_bf16(kA, qB, zero, 0, 0, 0);
        }
        if (kt == nkt - 1) {
            int query = q0w + l15;
#pragma unroll
            for (int nt = 0; nt < 8; ++nt)
#pragma unroll
                for (int r = 0; r < 4; ++r) {
                    int key = k0 + nt * 16 + quad * 4 + r;
                    if (key > query) s[nt][r] = -1e30f;
                }
        }
        float rs = 0.f;
#pragma unroll
        for (int nt = 0; nt < 8; ++nt)
#pragma unroll
            for (int r = 0; r < 4; ++r) {
                float p = exp2f(s[nt][r]);   // masked -> exp2(-1e30)=0
                s[nt][r] = p;
                rs += p;
            }
        rs += __shfl_xor(rs, 16);
        rs += __shfl_xor(rs, 32);
        l_i += rs;
#pragma unroll
        for (int nt = 0; nt < 8; ++nt) {
            u2v pw;
            pw.x = pack_bf2(s[nt][0], s[nt][1]);
            pw.y = pack_bf2(s[nt][2], s[nt][3]);
            *(u2v*)&Pw[l15 * 136 + nt * 16 + quad * 4] = pw;
        }
#pragma unroll
        for (int ks = 0; ks < 4; ++ks) {
            s8v aP = *(const s8v*)&Pw[l15 * 136 + ks * 32 + quad * 8];
            s8v v0 = *(const s8v*)&Vtb[l15 * 152 + ks * 32 + quad * 8];
            s8v v1 = *(const s8v*)&Vtb[(16 + l15) * 152 + ks * 32 + quad * 8];
            O0 = __builtin_amdgcn_mfma_f32_16x16x32_bf16(aP, v0, O0, 0, 0, 0);
            O1 = __builtin_amdgcn_mfma_f32_16x16x32_bf16(aP, v1, O1, 0, 0, 0);
        }
        if (kt == nkt - 1) {
#pragma unroll
            for (int r = 0; r < 4; ++r) {
                float linv = 1.f / __shfl(l_i, quad * 4 + r);
                int row = q0w + quad * 4 + r;
                size_t base = (size_t)(b * T_ + row) * D_ + h * DK_;
                AO[base + l15]      = f2bf(O0[r] * linv);
                AO[base + 16 + l15] = f2bf(O1[r] * linv);
            }
        }
    }
}

extern "C" void kernel_launch(void* const* d_in, const int* in_sizes, int n_in,
                              void* d_out, int out_size, void* d_ws, size_t ws_size,
                              hipStream_t stream)
{
    const float* emb  = (const float*)d_in[0];
    const int*   toks = (const int*)d_in[1];
    const float* tokE = (const float*)d_in[4];
    const float* pe   = (const float*)d_in[5];
    const float* Wq   = (const float*)d_in[6];
    const float* Wk   = (const float*)d_in[7];
    const float* Wv   = (const float*)d_in[8];
    const float* Wo   = (const float*)d_in[9];
    const float* bo   = (const float*)d_in[10];
    const float* g1   = (const float*)d_in[11];
    const float* be1  = (const float*)d_in[12];
    const float* W1   = (const float*)d_in[13];
    const float* b1   = (const float*)d_in[14];
    const float* W2   = (const float*)d_in[15];
    const float* b2   = (const float*)d_in[16];
    const float* g2   = (const float*)d_in[17];
    const float* be2  = (const float*)d_in[18];
    float* out = (float*)d_out;

    unsigned short* ws = (unsigned short*)d_ws;
    size_t off = 0;
    const size_t XSZ = (size_t)B_ * T_ * D_;
    unsigned short* Xa    = ws + off; off += XSZ;
    unsigned short* Xb    = ws + off; off += XSZ;   // unused (layout stability)
    unsigned short* Qh    = ws + off; off += XSZ;
    unsigned short* Kh    = ws + off; off += XSZ;
    unsigned short* VTb   = ws + off; off += XSZ;
    unsigned short* AOb   = ws + off; off += XSZ;
    unsigned short* Hb    = ws + off; off += (size_t)B_ * T_ * DFF_;  // unused
    unsigned short* WqkvT = ws + off; off += (size_t)L_ * 3 * D_ * D_;
    unsigned short* WoT   = ws + off; off += (size_t)L_ * D_ * D_;
    unsigned short* W1T   = ws + off; off += (size_t)L_ * D_ * DFF_;
    unsigned short* W2T   = ws + off; off += (size_t)L_ * DFF_ * D_;
    (void)ws_size; (void)in_sizes; (void)n_in; (void)out_size;
    (void)Xb; (void)Hb;

    prep_k<<<dim3(2048), 256, 0, stream>>>(emb, toks, tokE, pe, Xa,
                                           Wq, Wk, Wv, Wo, W1, W2,
                                           WqkvT, WoT, W1T, W2T);

    for (int l = 0; l < L_; ++l) {
        const unsigned short* wqkv = WqkvT + (size_t)l * 3 * D_ * D_;
        const unsigned short* wo   = WoT + (size_t)l * D_ * D_;
        const unsigned short* w1   = W1T + (size_t)l * D_ * DFF_;
        const unsigned short* w2   = W2T + (size_t)l * DFF_ * D_;
        const int last = (l == L_ - 1);

        gemm64_k<<<dim3(128, 12), 256, 0, stream>>>(Xa, wqkv, nullptr,
                                                    Qh, Kh, VTb, nullptr, D_, D_, 0);
        attn_k<<<dim3(16, 32), 256, 0, stream>>>(Qh, Kh, VTb, AOb);
        tail32_k<<<dim3(256), 512, 0, stream>>>(AOb, wo, bo + l * D_, Xa,
                                                g1 + l * D_, be1 + l * D_,
                                                w1, b1 + l * DFF_,
                                                w2, b2 + l * D_,
                                                g2 + l * D_, be2 + l * D_,
                                                Xa, out, last);
    }
}

// Round 6
// 256.196 us; speedup vs baseline: 1.7745x; 1.0255x over previous
//
#include <hip/hip_runtime.h>
#include <cstdint>
#include <cstddef>

#define B_   4
#define S_   2047
#define T_   2048
#define D_   256
#define H_   8
#define DK_  32
#define DFF_ 512
#define L_   2

typedef short          s8v  __attribute__((ext_vector_type(8)));
typedef float          f4v  __attribute__((ext_vector_type(4)));
typedef unsigned short u8v  __attribute__((ext_vector_type(8)));
typedef unsigned int   u2v  __attribute__((ext_vector_type(2)));
typedef unsigned int   uint32;

union U8 { u8v v; unsigned short e[8]; };

__device__ __forceinline__ float bf2f(unsigned short h) {
    unsigned int u = ((unsigned int)h) << 16;
    float f; __builtin_memcpy(&f, &u, 4); return f;
}
__device__ __forceinline__ unsigned short f2bf(float f) {
    unsigned int u; __builtin_memcpy(&u, &f, 4);
    u += 0x7fffu + ((u >> 16) & 1u);        // RNE
    return (unsigned short)(u >> 16);
}
__device__ __forceinline__ uint32 pack_bf2(float lo, float hi) {
    uint32 a, b;
    __builtin_memcpy(&a, &lo, 4); __builtin_memcpy(&b, &hi, 4);
    a += 0x8000u; b += 0x8000u;
    return __builtin_amdgcn_perm(b, a, 0x07060302);  // hi16(b)<<16 | hi16(a)
}

// log2(e)/sqrt(32): Q pre-scale so softmax runs in base-2 (exp2 = bare v_exp_f32)
#define QSCALE2 0.25503485951542068f

// ------- prep: embed (blocks 0..1023) + ALL weight transposes (1024..2047) --
__global__ __launch_bounds__(256) void prep_k(
    const float* __restrict__ emb, const int* __restrict__ toks,
    const float* __restrict__ tokE, const float* __restrict__ pe,
    unsigned short* __restrict__ X,
    const float* __restrict__ Wq, const float* __restrict__ Wk,
    const float* __restrict__ Wv, const float* __restrict__ Wo,
    const float* __restrict__ W1, const float* __restrict__ W2,
    unsigned short* __restrict__ WqkvT, unsigned short* __restrict__ WoT,
    unsigned short* __restrict__ W1T, unsigned short* __restrict__ W2T)
{
    __shared__ float tile[32][33];
    if (blockIdx.x < 1024) {
        int idx = blockIdx.x * 256 + threadIdx.x;      // B*T*32
        int d8 = (idx & 31) * 8;
        int t  = (idx >> 5) & (T_ - 1);
        int b  = idx >> 16;
        const float* src = (t == 0) ? (emb + b * D_)
                                    : (tokE + (size_t)toks[b * S_ + t - 1] * D_);
        const float* p = pe + (size_t)t * D_ + d8;
        U8 o;
#pragma unroll
        for (int j = 0; j < 8; ++j) o.e[j] = f2bf(src[d8 + j] + p[j]);
        *(u8v*)(X + (size_t)(b * T_ + t) * D_ + d8) = o.v;
        return;
    }
    int idx = blockIdx.x - 1024;
    const float* src; unsigned short* dst; int R, C, tr, tc;
    if (idx < 512) {
        int w = idx >> 7, rem = idx & 127, l = rem >> 6, t = rem & 63;
        tr = t >> 3; tc = t & 7; R = 256; C = 256;
        src = (w == 0 ? Wq : w == 1 ? Wk : w == 2 ? Wv : Wo) + (size_t)l * 65536;
        dst = (w < 3) ? WqkvT + (size_t)l * 196608 + (size_t)w * 65536
                      : WoT + (size_t)l * 65536;
    } else if (idx < 768) {
        int rem = idx - 512, l = rem >> 7, t = rem & 127;
        tr = t >> 4; tc = t & 15; R = 256; C = 512;
        src = W1 + (size_t)l * 131072; dst = W1T + (size_t)l * 131072;
    } else {
        int rem = idx - 768, l = rem >> 7, t = rem & 127;
        tr = t >> 3; tc = t & 7; R = 512; C = 256;
        src = W2 + (size_t)l * 131072; dst = W2T + (size_t)l * 131072;
    }
    int x = threadIdx.x & 31, y = threadIdx.x >> 5;
    int r0 = tr * 32, c0 = tc * 32;
#pragma unroll
    for (int i = 0; i < 32; i += 8) tile[y + i][x] = src[(size_t)(r0 + y + i) * C + c0 + x];
    __syncthreads();
#pragma unroll
    for (int i = 0; i < 32; i += 8)
        dst[(size_t)(c0 + y + i) * R + r0 + x] = f2bf(tile[x][y + i]);
}

// ---- GEMM 64x64 tile, BK=64, reg-prefetch.  C = A[M,K] @ WT[N,K]^T ---------
// mode 0: QKV. blockIdx.y in [0,12): sub=y>>2 (0:Q scaled,1:K,2:V transposed)
__global__ __launch_bounds__(256) void gemm64_k(
    const unsigned short* __restrict__ A, const unsigned short* __restrict__ WT,
    const float* __restrict__ bias,
    unsigned short* __restrict__ oq, unsigned short* __restrict__ ok,
    unsigned short* __restrict__ ov, unsigned short* __restrict__ out,
    int K, int Ntot, int mode)
{
    __shared__ unsigned short At[64 * 72];
    __shared__ unsigned short Wt[64 * 72];
    const int tid = threadIdx.x;
    const int wave = tid >> 6, lane = tid & 63, l15 = lane & 15, quad = lane >> 4;
    const int m0 = blockIdx.x * 64, n0g = blockIdx.y * 64;

    f4v acc[4];
#pragma unroll
    for (int i = 0; i < 4; ++i) acc[i] = (f4v){0.f, 0.f, 0.f, 0.f};

    const int arow = tid >> 2, acg = (tid & 3) * 16;
    const unsigned short* ag = A + (size_t)(m0 + arow) * K + acg;
    const unsigned short* wg = WT + (size_t)(n0g + arow) * K + acg;
    u8v a0 = *(const u8v*)ag, a1 = *(const u8v*)(ag + 8);
    u8v w0 = *(const u8v*)wg, w1 = *(const u8v*)(wg + 8);

    const int niter = K >> 6;
    for (int kk = 0; kk < niter; ++kk) {
        *(u8v*)&At[arow * 72 + acg] = a0; *(u8v*)&At[arow * 72 + acg + 8] = a1;
        *(u8v*)&Wt[arow * 72 + acg] = w0; *(u8v*)&Wt[arow * 72 + acg + 8] = w1;
        __syncthreads();
        if (kk + 1 < niter) {
            int o = (kk + 1) * 64;
            a0 = *(const u8v*)(ag + o); a1 = *(const u8v*)(ag + o + 8);
            w0 = *(const u8v*)(wg + o); w1 = *(const u8v*)(wg + o + 8);
        }
#pragma unroll
        for (int ks = 0; ks < 2; ++ks) {
            s8v aF = *(const s8v*)&At[(wave * 16 + l15) * 72 + ks * 32 + quad * 8];
#pragma unroll
            for (int nt = 0; nt < 4; ++nt) {
                s8v wF = *(const s8v*)&Wt[(nt * 16 + l15) * 72 + ks * 32 + quad * 8];
                acc[nt] = __builtin_amdgcn_mfma_f32_16x16x32_bf16(aF, wF, acc[nt], 0, 0, 0);
            }
        }
        __syncthreads();
    }

    const int b = m0 >> 11, t0 = m0 & (T_ - 1);
    if (mode == 0) {
        int sub = blockIdx.y >> 2;
        int cb  = (blockIdx.y & 3) * 64;
        if (sub < 2) {
            unsigned short* dst = sub ? ok : oq;
            float sc = sub ? 1.f : QSCALE2;
#pragma unroll
            for (int nt = 0; nt < 4; ++nt) {
                int c = cb + nt * 16 + l15, hh = c >> 5, dk = c & 31;
#pragma unroll
                for (int r = 0; r < 4; ++r) {
                    int t = t0 + wave * 16 + quad * 4 + r;
                    dst[((size_t)(b * H_ + hh) * T_ + t) * DK_ + dk] = f2bf(acc[nt][r] * sc);
                }
            }
        } else {
            unsigned short* Vb = At;   // reuse: [64 cols][72]
#pragma unroll
            for (int nt = 0; nt < 4; ++nt) {
                int base = (nt * 16 + l15) * 72 + wave * 16 + quad * 4;
                *(uint32*)&Vb[base]     = pack_bf2(acc[nt][0], acc[nt][1]);
                *(uint32*)&Vb[base + 2] = pack_bf2(acc[nt][2], acc[nt][3]);
            }
            __syncthreads();
            int c = tid >> 2, chunk = tid & 3;
            int cg = cb + c, hh = cg >> 5, dk = cg & 31;
            unsigned short* dst = ov + ((size_t)(b * H_ + hh) * DK_ + dk) * T_ + t0 + chunk * 16;
            u8v v0 = *(u8v*)&Vb[c * 72 + chunk * 16];
            u8v v1 = *(u8v*)&Vb[c * 72 + chunk * 16 + 8];
            *(u8v*)dst = v0; *(u8v*)(dst + 8) = v1;
        }
    } else {
#pragma unroll
        for (int nt = 0; nt < 4; ++nt) {
            int c = n0g + nt * 16 + l15;
            float bv = bias[c];
#pragma unroll
            for (int r = 0; r < 4; ++r) {
                float v = acc[nt][r] + bv;
                v = v > 0.f ? v : 0.f;
                out[(size_t)(m0 + wave * 16 + quad * 4 + r) * Ntot + c] = f2bf(v);
            }
        }
    }
}

// ---- fused tail (R3-proven structure): U1 (AO@Wo+bo+resid,LN1) -> FF1 ------
// ---- (relu X1@W1+b1) -> U2 (H@W2+b2+resid(X1),LN2) -> Xout / f32 out ------
__global__ __launch_bounds__(512) void tail32_k(
    const unsigned short* __restrict__ AO,
    const unsigned short* __restrict__ WoTl, const float* __restrict__ bo,
    const unsigned short* __restrict__ Xres,
    const float* __restrict__ g1, const float* __restrict__ be1,
    const unsigned short* __restrict__ W1Tl, const float* __restrict__ b1,
    const unsigned short* __restrict__ W2Tl, const float* __restrict__ b2,
    const float* __restrict__ g2, const float* __restrict__ be2,
    unsigned short* __restrict__ Xout, float* __restrict__ fout, int last)
{
    __shared__ unsigned short Wt[256 * 72];
    __shared__ unsigned short As[32 * 72];
    __shared__ unsigned short X1s[32 * 264];
    __shared__ unsigned short Hs[32 * 520];
    __shared__ float LNsc[256];

    const int tid = threadIdx.x;
    const int wave = tid >> 6, lane = tid & 63, l15 = lane & 15, quad = lane >> 4;
    const int wr = wave >> 2, wc = wave & 3;
    const int m0 = blockIdx.x * 32;
    const int rbase = wr * 16 + quad * 4;

    const int wrow = tid >> 1, wcol = (tid & 1) * 32;
    const int arow = tid >> 3, acol = (tid & 7) * 8;

    f4v acc[4];
    u8v w0, w1, w2, w3, a0 = {0,0,0,0,0,0,0,0};

    const unsigned short* wgo = WoTl + (size_t)wrow * 256 + wcol;
    const unsigned short* wg1 = W1Tl + (size_t)wrow * 256 + wcol;
    const unsigned short* wg1b = W1Tl + (size_t)(256 + wrow) * 256 + wcol;
    const unsigned short* wg2 = W2Tl + (size_t)wrow * 512 + wcol;
    const unsigned short* ag  = AO + (size_t)(m0 + arow) * 256 + acol;

#define LDW(p, o) { w0 = *(const u8v*)((p)+(o)); w1 = *(const u8v*)((p)+(o)+8); \
                    w2 = *(const u8v*)((p)+(o)+16); w3 = *(const u8v*)((p)+(o)+24); }
#define STW { *(u8v*)&Wt[wrow*72+wcol] = w0; *(u8v*)&Wt[wrow*72+wcol+8] = w1; \
              *(u8v*)&Wt[wrow*72+wcol+16] = w2; *(u8v*)&Wt[wrow*72+wcol+24] = w3; }

    // ================= U1: AO @ WoT^T =================
#pragma unroll
    for (int i = 0; i < 4; ++i) acc[i] = (f4v){0.f, 0.f, 0.f, 0.f};
    LDW(wgo, 0);
    if (tid < 256) a0 = *(const u8v*)ag;
    for (int kk = 0; kk < 4; ++kk) {
        STW;
        if (tid < 256) *(u8v*)&As[arow * 72 + acol] = a0;
        __syncthreads();
        if (kk < 3) {
            LDW(wgo, (kk + 1) * 64);
            if (tid < 256) a0 = *(const u8v*)(ag + (kk + 1) * 64);
        } else {
            LDW(wg1, 0);
        }
#pragma unroll
        for (int ks = 0; ks < 2; ++ks) {
            s8v aF = *(const s8v*)&As[(wr * 16 + l15) * 72 + ks * 32 + quad * 8];
#pragma unroll
            for (int nt = 0; nt < 4; ++nt) {
                s8v wF = *(const s8v*)&Wt[(wc * 64 + nt * 16 + l15) * 72 + ks * 32 + quad * 8];
                acc[nt] = __builtin_amdgcn_mfma_f32_16x16x32_bf16(aF, wF, acc[nt], 0, 0, 0);
            }
        }
        __syncthreads();
    }
    // ---- epilogue U1: bias + resid(global X) + LN1 -> X1s ----
    {
        float ps[4] = {0,0,0,0}, pq[4] = {0,0,0,0};
#pragma unroll
        for (int nt = 0; nt < 4; ++nt) {
            int c = wc * 64 + nt * 16 + l15;
            float bv = bo[c];
#pragma unroll
            for (int r = 0; r < 4; ++r) {
                float v = acc[nt][r] + bv + bf2f(Xres[(size_t)(m0 + rbase + r) * D_ + c]);
                acc[nt][r] = v; ps[r] += v; pq[r] += v * v;
            }
        }
#pragma unroll
        for (int r = 0; r < 4; ++r) {
            float s = ps[r], q = pq[r];
            s += __shfl_xor(s, 1); q += __shfl_xor(q, 1);
            s += __shfl_xor(s, 2); q += __shfl_xor(q, 2);
            s += __shfl_xor(s, 4); q += __shfl_xor(q, 4);
            s += __shfl_xor(s, 8); q += __shfl_xor(q, 8);
            if (l15 == 0) { LNsc[(rbase + r) * 4 + wc] = s; LNsc[128 + (rbase + r) * 4 + wc] = q; }
        }
        __syncthreads();
#pragma unroll
        for (int r = 0; r < 4; ++r) {
            int row = rbase + r;
            float s = LNsc[row * 4] + LNsc[row * 4 + 1] + LNsc[row * 4 + 2] + LNsc[row * 4 + 3];
            float q = LNsc[128 + row * 4] + LNsc[128 + row * 4 + 1] + LNsc[128 + row * 4 + 2] + LNsc[128 + row * 4 + 3];
            float m = s * (1.f / 256.f);
            float rs = rsqrtf(q * (1.f / 256.f) - m * m + 1e-5f);
#pragma unroll
            for (int nt = 0; nt < 4; ++nt) {
                int c = wc * 64 + nt * 16 + l15;
                X1s[row * 264 + c] = f2bf((acc[nt][r] - m) * rs * g1[c] + be1[c]);
            }
        }
        __syncthreads();
    }

    // ================= FF1-a: H[:,0:256] = relu(X1 @ W1T[0:256]^T + b1) =====
#pragma unroll
    for (int i = 0; i < 4; ++i) acc[i] = (f4v){0.f, 0.f, 0.f, 0.f};
    for (int kk = 0; kk < 4; ++kk) {
        STW;
        __syncthreads();
        if (kk < 3) LDW(wg1, (kk + 1) * 64) else LDW(wg1b, 0);
#pragma unroll
        for (int ks = 0; ks < 2; ++ks) {
            s8v aF = *(const s8v*)&X1s[(wr * 16 + l15) * 264 + kk * 64 + ks * 32 + quad * 8];
#pragma unroll
            for (int nt = 0; nt < 4; ++nt) {
                s8v wF = *(const s8v*)&Wt[(wc * 64 + nt * 16 + l15) * 72 + ks * 32 + quad * 8];
                acc[nt] = __builtin_amdgcn_mfma_f32_16x16x32_bf16(aF, wF, acc[nt], 0, 0, 0);
            }
        }
        __syncthreads();
    }
#pragma unroll
    for (int nt = 0; nt < 4; ++nt) {
        int c = wc * 64 + nt * 16 + l15;
        float bv = b1[c];
#pragma unroll
        for (int r = 0; r < 4; ++r) {
            float v = acc[nt][r] + bv; v = v > 0.f ? v : 0.f;
            Hs[(rbase + r) * 520 + c] = f2bf(v);
        }
    }

    // ================= FF1-b: H[:,256:512] =================
#pragma unroll
    for (int i = 0; i < 4; ++i) acc[i] = (f4v){0.f, 0.f, 0.f, 0.f};
    for (int kk = 0; kk < 4; ++kk) {
        STW;
        __syncthreads();
        if (kk < 3) LDW(wg1b, (kk + 1) * 64) else LDW(wg2, 0);
#pragma unroll
        for (int ks = 0; ks < 2; ++ks) {
            s8v aF = *(const s8v*)&X1s[(wr * 16 + l15) * 264 + kk * 64 + ks * 32 + quad * 8];
#pragma unroll
            for (int nt = 0; nt < 4; ++nt) {
                s8v wF = *(const s8v*)&Wt[(wc * 64 + nt * 16 + l15) * 72 + ks * 32 + quad * 8];
                acc[nt] = __builtin_amdgcn_mfma_f32_16x16x32_bf16(aF, wF, acc[nt], 0, 0, 0);
            }
        }
        __syncthreads();
    }
#pragma unroll
    for (int nt = 0; nt < 4; ++nt) {
        int c = wc * 64 + nt * 16 + l15;
        float bv = b1[256 + c];
#pragma unroll
        for (int r = 0; r < 4; ++r) {
            float v = acc[nt][r] + bv; v = v > 0.f ? v : 0.f;
            Hs[(rbase + r) * 520 + 256 + c] = f2bf(v);
        }
    }

    // ================= U2: H @ W2T^T =================
#pragma unroll
    for (int i = 0; i < 4; ++i) acc[i] = (f4v){0.f, 0.f, 0.f, 0.f};
    for (int kk = 0; kk < 8; ++kk) {
        STW;
        __syncthreads();
        if (kk < 7) LDW(wg2, (kk + 1) * 64);
#pragma unroll
        for (int ks = 0; ks < 2; ++ks) {
            s8v aF = *(const s8v*)&Hs[(wr * 16 + l15) * 520 + kk * 64 + ks * 32 + quad * 8];
#pragma unroll
            for (int nt = 0; nt < 4; ++nt) {
                s8v wF = *(const s8v*)&Wt[(wc * 64 + nt * 16 + l15) * 72 + ks * 32 + quad * 8];
                acc[nt] = __builtin_amdgcn_mfma_f32_16x16x32_bf16(aF, wF, acc[nt], 0, 0, 0);
            }
        }
        __syncthreads();
    }
    // ---- epilogue U2: bias + resid(X1s) + LN2 -> Xout / f32 out ----
    {
        float ps[4] = {0,0,0,0}, pq[4] = {0,0,0,0};
#pragma unroll
        for (int nt = 0; nt < 4; ++nt) {
            int c = wc * 64 + nt * 16 + l15;
            float bv = b2[c];
#pragma unroll
            for (int r = 0; r < 4; ++r) {
                float v = acc[nt][r] + bv + bf2f(X1s[(rbase + r) * 264 + c]);
                acc[nt][r] = v; ps[r] += v; pq[r] += v * v;
            }
        }
#pragma unroll
        for (int r = 0; r < 4; ++r) {
            float s = ps[r], q = pq[r];
            s += __shfl_xor(s, 1); q += __shfl_xor(q, 1);
            s += __shfl_xor(s, 2); q += __shfl_xor(q, 2);
            s += __shfl_xor(s, 4); q += __shfl_xor(q, 4);
            s += __shfl_xor(s, 8); q += __shfl_xor(q, 8);
            if (l15 == 0) { LNsc[(rbase + r) * 4 + wc] = s; LNsc[128 + (rbase + r) * 4 + wc] = q; }
        }
        __syncthreads();
#pragma unroll
        for (int r = 0; r < 4; ++r) {
            int row = rbase + r;
            float s = LNsc[row * 4] + LNsc[row * 4 + 1] + LNsc[row * 4 + 2] + LNsc[row * 4 + 3];
            float q = LNsc[128 + row * 4] + LNsc[128 + row * 4 + 1] + LNsc[128 + row * 4 + 2] + LNsc[128 + row * 4 + 3];
            float m = s * (1.f / 256.f);
            float rs = rsqrtf(q * (1.f / 256.f) - m * m + 1e-5f);
#pragma unroll
            for (int nt = 0; nt < 4; ++nt) {
                int c = wc * 64 + nt * 16 + l15;
                float val = (acc[nt][r] - m) * rs * g2[c] + be2[c];
                if (!last) {
                    Xout[(size_t)(m0 + row) * D_ + c] = f2bf(val);
                } else {
                    int gr = m0 + row;
                    int t = gr & (T_ - 1), bb = gr >> 11;
                    if (t) fout[((size_t)bb * S_ + t - 1) * D_ + c] = val;
                }
            }
        }
    }
#undef LDW
#undef STW
}

// ---- flash attention, 8-WAVE blocks: wave-group 0 handles q-tile x, group 1
// handles q-tile 31-x IN PARALLEL, sharing K/V staging.  Block runs
// max(nk0,nk1) = nk(31-x) k-tiles (avg 12.5 vs 17 sequential).  LDS 74.7KB
// -> 2 blocks/CU -> 16 waves/CU (was 8).  __launch_bounds__(512,4) pins
// VGPR<=128 so occupancy is LDS-limited, not register-limited.
#define KTP 5120   // 128*40 u16 per K buffer
#define VTP 4864   // 32*152 u16 per V buffer
__global__ __launch_bounds__(512, 4) void attn_k(
    const unsigned short* __restrict__ Qh, const unsigned short* __restrict__ Kh,
    const unsigned short* __restrict__ VT, unsigned short* __restrict__ AO)
{
    __shared__ unsigned short Kt[2 * KTP];       // [buf][key][dk] pitch 40
    __shared__ unsigned short Vt[2 * VTP];       // [buf][dk][key] pitch 152
    __shared__ unsigned short Ps[8][16 * 136];   // per-wave P [query][key]

    const int tid = threadIdx.x, wave = tid >> 6, lane = tid & 63;
    const int l15 = lane & 15, quad = lane >> 4;
    const int grp = wave >> 2, wl = wave & 3;
    const int bh = blockIdx.y, b = bh >> 3, h = bh & 7;
    const size_t hoff = (size_t)bh * T_ * DK_;
    unsigned short* Pw = &Ps[wave][0];

    const int x = blockIdx.x;                 // 0..15
    const int qt = grp ? 31 - x : x;          // my group's q-tile
    const int nkt = qt / 2 + 1;               // my group's causal k-tiles
    const int nmax = (31 - x) / 2 + 1;        // block-wide k-tiles (grp1 >= grp0)

    // staging: 512 threads, 16B each (K: 128x32, V: 32x128)
    const int krow = tid >> 2, kcol = (tid & 3) * 8;
    const int vdk = tid >> 4, vc = (tid & 15) * 8;
    const unsigned short* kgp = Kh + hoff + (size_t)krow * DK_ + kcol;
    const unsigned short* vgp = VT + ((size_t)bh * DK_ + vdk) * T_ + vc;

    u8v kr = *(const u8v*)kgp;
    u8v vr = *(const u8v*)vgp;

    const int q0w = qt * 64 + wl * 16;
    const s8v qB = *(const s8v*)(Qh + hoff + (size_t)(q0w + l15) * DK_ + quad * 8);
    f4v O0 = {0,0,0,0}, O1 = {0,0,0,0};
    float l_i = 0.f;

    for (int kt = 0; kt < nmax; ++kt) {
        unsigned short* Ktb = Kt + (kt & 1) * KTP;
        unsigned short* Vtb = Vt + (kt & 1) * VTP;
        *(u8v*)&Ktb[krow * 40 + kcol] = kr;
        *(u8v*)&Vtb[vdk * 152 + vc]   = vr;
        __syncthreads();    // single barrier/tile (dbuf: next iter writes buf^1,
                            // whose last readers all passed THIS barrier)
        if (kt + 1 < nmax) {
            kr = *(const u8v*)(kgp + (size_t)(kt + 1) * 128 * DK_);
            vr = *(const u8v*)(vgp + (kt + 1) * 128);
        }
        if (kt < nkt) {     // group-uniform branch; finished group only stages
            const int k0 = kt * 128;
            f4v s[8];
            f4v zero = {0,0,0,0};
#pragma unroll
            for (int nt = 0; nt < 8; ++nt) {
                s8v kA = *(const s8v*)&Ktb[(nt * 16 + l15) * 40 + quad * 8];
                s[nt] = __builtin_amdgcn_mfma_f32_16x16x32_bf16(kA, qB, zero, 0, 0, 0);
            }
            if (kt == nkt - 1) {
                int query = q0w + l15;
#pragma unroll
                for (int nt = 0; nt < 8; ++nt)
#pragma unroll
                    for (int r = 0; r < 4; ++r) {
                        int key = k0 + nt * 16 + quad * 4 + r;
                        if (key > query) s[nt][r] = -1e30f;
                    }
            }
            float rs = 0.f;
#pragma unroll
            for (int nt = 0; nt < 8; ++nt)
#pragma unroll
                for (int r = 0; r < 4; ++r) {
                    float p = exp2f(s[nt][r]);   // masked -> exp2(-1e30)=0
                    s[nt][r] = p;
                    rs += p;
                }
            rs += __shfl_xor(rs, 16);
            rs += __shfl_xor(rs, 32);
            l_i += rs;
#pragma unroll
            for (int nt = 0; nt < 8; ++nt) {
                u2v pw;
                pw.x = pack_bf2(s[nt][0], s[nt][1]);
                pw.y = pack_bf2(s[nt][2], s[nt][3]);
                *(u2v*)&Pw[l15 * 136 + nt * 16 + quad * 4] = pw;
            }
#pragma unroll
            for (int ks = 0; ks < 4; ++ks) {
                s8v aP = *(const s8v*)&Pw[l15 * 136 + ks * 32 + quad * 8];
                s8v v0 = *(const s8v*)&Vtb[l15 * 152 + ks * 32 + quad * 8];
                s8v v1 = *(const s8v*)&Vtb[(16 + l15) * 152 + ks * 32 + quad * 8];
                O0 = __builtin_amdgcn_mfma_f32_16x16x32_bf16(aP, v0, O0, 0, 0, 0);
                O1 = __builtin_amdgcn_mfma_f32_16x16x32_bf16(aP, v1, O1, 0, 0, 0);
            }
            if (kt == nkt - 1) {
#pragma unroll
                for (int r = 0; r < 4; ++r) {
                    float linv = 1.f / __shfl(l_i, quad * 4 + r);
                    int row = q0w + quad * 4 + r;
                    size_t base = (size_t)(b * T_ + row) * D_ + h * DK_;
                    AO[base + l15]      = f2bf(O0[r] * linv);
                    AO[base + 16 + l15] = f2bf(O1[r] * linv);
                }
            }
        }
    }
}

extern "C" void kernel_launch(void* const* d_in, const int* in_sizes, int n_in,
                              void* d_out, int out_size, void* d_ws, size_t ws_size,
                              hipStream_t stream)
{
    const float* emb  = (const float*)d_in[0];
    const int*   toks = (const int*)d_in[1];
    const float* tokE = (const float*)d_in[4];
    const float* pe   = (const float*)d_in[5];
    const float* Wq   = (const float*)d_in[6];
    const float* Wk   = (const float*)d_in[7];
    const float* Wv   = (const float*)d_in[8];
    const float* Wo   = (const float*)d_in[9];
    const float* bo   = (const float*)d_in[10];
    const float* g1   = (const float*)d_in[11];
    const float* be1  = (const float*)d_in[12];
    const float* W1   = (const float*)d_in[13];
    const float* b1   = (const float*)d_in[14];
    const float* W2   = (const float*)d_in[15];
    const float* b2   = (const float*)d_in[16];
    const float* g2   = (const float*)d_in[17];
    const float* be2  = (const float*)d_in[18];
    float* out = (float*)d_out;

    unsigned short* ws = (unsigned short*)d_ws;
    size_t off = 0;
    const size_t XSZ = (size_t)B_ * T_ * D_;
    unsigned short* Xa    = ws + off; off += XSZ;
    unsigned short* Xb    = ws + off; off += XSZ;   // unused (layout stability)
    unsigned short* Qh    = ws + off; off += XSZ;
    unsigned short* Kh    = ws + off; off += XSZ;
    unsigned short* VTb   = ws + off; off += XSZ;
    unsigned short* AOb   = ws + off; off += XSZ;
    unsigned short* Hb    = ws + off; off += (size_t)B_ * T_ * DFF_;  // unused
    unsigned short* WqkvT = ws + off; off += (size_t)L_ * 3 * D_ * D_;
    unsigned short* WoT   = ws + off; off += (size_t)L_ * D_ * D_;
    unsigned short* W1T   = ws + off; off += (size_t)L_ * D_ * DFF_;
    unsigned short* W2T   = ws + off; off += (size_t)L_ * DFF_ * D_;
    (void)ws_size; (void)in_sizes; (void)n_in; (void)out_size;
    (void)Xb; (void)Hb;

    prep_k<<<dim3(2048), 256, 0, stream>>>(emb, toks, tokE, pe, Xa,
                                           Wq, Wk, Wv, Wo, W1, W2,
                                           WqkvT, WoT, W1T, W2T);

    for (int l = 0; l < L_; ++l) {
        const unsigned short* wqkv = WqkvT + (size_t)l * 3 * D_ * D_;
        const unsigned short* wo   = WoT + (size_t)l * D_ * D_;
        const unsigned short* w1   = W1T + (size_t)l * D_ * DFF_;
        const unsigned short* w2   = W2T + (size_t)l * DFF_ * D_;
        const int last = (l == L_ - 1);

        gemm64_k<<<dim3(128, 12), 256, 0, stream>>>(Xa, wqkv, nullptr,
                                                    Qh, Kh, VTb, nullptr, D_, D_, 0);
        attn_k<<<dim3(16, 32), 512, 0, stream>>>(Qh, Kh, VTb, AOb);
        tail32_k<<<dim3(256), 512, 0, stream>>>(AOb, wo, bo + l * D_, Xa,
                                                g1 + l * D_, be1 + l * D_,
                                                w1, b1 + l * DFF_,
                                                w2, b2 + l * D_,
                                                g2 + l * D_, be2 + l * D_,
                                                Xa, out, last);
    }
}

// Round 7
// 246.541 us; speedup vs baseline: 1.8440x; 1.0392x over previous
//
#include <hip/hip_runtime.h>
#include <cstdint>
#include <cstddef>

#define B_   4
#define S_   2047
#define T_   2048
#define D_   256
#define H_   8
#define DK_  32
#define DFF_ 512
#define L_   2

typedef short          s8v  __attribute__((ext_vector_type(8)));
typedef float          f4v  __attribute__((ext_vector_type(4)));
typedef unsigned short u8v  __attribute__((ext_vector_type(8)));
typedef unsigned int   u2v  __attribute__((ext_vector_type(2)));
typedef unsigned int   uint32;

union U8 { u8v v; unsigned short e[8]; };

__device__ __forceinline__ float bf2f(unsigned short h) {
    unsigned int u = ((unsigned int)h) << 16;
    float f; __builtin_memcpy(&f, &u, 4); return f;
}
__device__ __forceinline__ unsigned short f2bf(float f) {
    unsigned int u; __builtin_memcpy(&u, &f, 4);
    u += 0x7fffu + ((u >> 16) & 1u);        // RNE
    return (unsigned short)(u >> 16);
}
__device__ __forceinline__ uint32 pack_bf2(float lo, float hi) {
    uint32 a, b;
    __builtin_memcpy(&a, &lo, 4); __builtin_memcpy(&b, &hi, 4);
    a += 0x8000u; b += 0x8000u;
    return __builtin_amdgcn_perm(b, a, 0x07060302);  // hi16(b)<<16 | hi16(a)
}

// log2(e)/sqrt(32): Q pre-scale so softmax runs in base-2 (exp2 = bare v_exp_f32)
#define QSCALE2 0.25503485951542068f

// ------- prep: embed (blocks 0..1023) + ALL weight transposes (1024..2047) --
__global__ __launch_bounds__(256) void prep_k(
    const float* __restrict__ emb, const int* __restrict__ toks,
    const float* __restrict__ tokE, const float* __restrict__ pe,
    unsigned short* __restrict__ X,
    const float* __restrict__ Wq, const float* __restrict__ Wk,
    const float* __restrict__ Wv, const float* __restrict__ Wo,
    const float* __restrict__ W1, const float* __restrict__ W2,
    unsigned short* __restrict__ WqkvT, unsigned short* __restrict__ WoT,
    unsigned short* __restrict__ W1T, unsigned short* __restrict__ W2T)
{
    __shared__ float tile[32][33];
    if (blockIdx.x < 1024) {
        int idx = blockIdx.x * 256 + threadIdx.x;      // B*T*32
        int d8 = (idx & 31) * 8;
        int t  = (idx >> 5) & (T_ - 1);
        int b  = idx >> 16;
        const float* src = (t == 0) ? (emb + b * D_)
                                    : (tokE + (size_t)toks[b * S_ + t - 1] * D_);
        const float* p = pe + (size_t)t * D_ + d8;
        U8 o;
#pragma unroll
        for (int j = 0; j < 8; ++j) o.e[j] = f2bf(src[d8 + j] + p[j]);
        *(u8v*)(X + (size_t)(b * T_ + t) * D_ + d8) = o.v;
        return;
    }
    int idx = blockIdx.x - 1024;
    const float* src; unsigned short* dst; int R, C, tr, tc;
    if (idx < 512) {
        int w = idx >> 7, rem = idx & 127, l = rem >> 6, t = rem & 63;
        tr = t >> 3; tc = t & 7; R = 256; C = 256;
        src = (w == 0 ? Wq : w == 1 ? Wk : w == 2 ? Wv : Wo) + (size_t)l * 65536;
        dst = (w < 3) ? WqkvT + (size_t)l * 196608 + (size_t)w * 65536
                      : WoT + (size_t)l * 65536;
    } else if (idx < 768) {
        int rem = idx - 512, l = rem >> 7, t = rem & 127;
        tr = t >> 4; tc = t & 15; R = 256; C = 512;
        src = W1 + (size_t)l * 131072; dst = W1T + (size_t)l * 131072;
    } else {
        int rem = idx - 768, l = rem >> 7, t = rem & 127;
        tr = t >> 3; tc = t & 7; R = 512; C = 256;
        src = W2 + (size_t)l * 131072; dst = W2T + (size_t)l * 131072;
    }
    int x = threadIdx.x & 31, y = threadIdx.x >> 5;
    int r0 = tr * 32, c0 = tc * 32;
#pragma unroll
    for (int i = 0; i < 32; i += 8) tile[y + i][x] = src[(size_t)(r0 + y + i) * C + c0 + x];
    __syncthreads();
#pragma unroll
    for (int i = 0; i < 32; i += 8)
        dst[(size_t)(c0 + y + i) * R + r0 + x] = f2bf(tile[x][y + i]);
}

// ---- GEMM 64x64 tile, BK=64, reg-prefetch.  C = A[M,K] @ WT[N,K]^T ---------
// mode 0: QKV. blockIdx.y in [0,12): sub=y>>2 (0:Q scaled,1:K,2:V transposed)
__global__ __launch_bounds__(256) void gemm64_k(
    const unsigned short* __restrict__ A, const unsigned short* __restrict__ WT,
    const float* __restrict__ bias,
    unsigned short* __restrict__ oq, unsigned short* __restrict__ ok,
    unsigned short* __restrict__ ov, unsigned short* __restrict__ out,
    int K, int Ntot, int mode)
{
    __shared__ unsigned short At[64 * 72];
    __shared__ unsigned short Wt[64 * 72];
    const int tid = threadIdx.x;
    const int wave = tid >> 6, lane = tid & 63, l15 = lane & 15, quad = lane >> 4;
    const int m0 = blockIdx.x * 64, n0g = blockIdx.y * 64;

    f4v acc[4];
#pragma unroll
    for (int i = 0; i < 4; ++i) acc[i] = (f4v){0.f, 0.f, 0.f, 0.f};

    const int arow = tid >> 2, acg = (tid & 3) * 16;
    const unsigned short* ag = A + (size_t)(m0 + arow) * K + acg;
    const unsigned short* wg = WT + (size_t)(n0g + arow) * K + acg;
    u8v a0 = *(const u8v*)ag, a1 = *(const u8v*)(ag + 8);
    u8v w0 = *(const u8v*)wg, w1 = *(const u8v*)(wg + 8);

    const int niter = K >> 6;
    for (int kk = 0; kk < niter; ++kk) {
        *(u8v*)&At[arow * 72 + acg] = a0; *(u8v*)&At[arow * 72 + acg + 8] = a1;
        *(u8v*)&Wt[arow * 72 + acg] = w0; *(u8v*)&Wt[arow * 72 + acg + 8] = w1;
        __syncthreads();
        if (kk + 1 < niter) {
            int o = (kk + 1) * 64;
            a0 = *(const u8v*)(ag + o); a1 = *(const u8v*)(ag + o + 8);
            w0 = *(const u8v*)(wg + o); w1 = *(const u8v*)(wg + o + 8);
        }
#pragma unroll
        for (int ks = 0; ks < 2; ++ks) {
            s8v aF = *(const s8v*)&At[(wave * 16 + l15) * 72 + ks * 32 + quad * 8];
#pragma unroll
            for (int nt = 0; nt < 4; ++nt) {
                s8v wF = *(const s8v*)&Wt[(nt * 16 + l15) * 72 + ks * 32 + quad * 8];
                acc[nt] = __builtin_amdgcn_mfma_f32_16x16x32_bf16(aF, wF, acc[nt], 0, 0, 0);
            }
        }
        __syncthreads();
    }

    const int b = m0 >> 11, t0 = m0 & (T_ - 1);
    if (mode == 0) {
        int sub = blockIdx.y >> 2;
        int cb  = (blockIdx.y & 3) * 64;
        if (sub < 2) {
            unsigned short* dst = sub ? ok : oq;
            float sc = sub ? 1.f : QSCALE2;
#pragma unroll
            for (int nt = 0; nt < 4; ++nt) {
                int c = cb + nt * 16 + l15, hh = c >> 5, dk = c & 31;
#pragma unroll
                for (int r = 0; r < 4; ++r) {
                    int t = t0 + wave * 16 + quad * 4 + r;
                    dst[((size_t)(b * H_ + hh) * T_ + t) * DK_ + dk] = f2bf(acc[nt][r] * sc);
                }
            }
        } else {
            unsigned short* Vb = At;   // reuse: [64 cols][72]
#pragma unroll
            for (int nt = 0; nt < 4; ++nt) {
                int base = (nt * 16 + l15) * 72 + wave * 16 + quad * 4;
                *(uint32*)&Vb[base]     = pack_bf2(acc[nt][0], acc[nt][1]);
                *(uint32*)&Vb[base + 2] = pack_bf2(acc[nt][2], acc[nt][3]);
            }
            __syncthreads();
            int c = tid >> 2, chunk = tid & 3;
            int cg = cb + c, hh = cg >> 5, dk = cg & 31;
            unsigned short* dst = ov + ((size_t)(b * H_ + hh) * DK_ + dk) * T_ + t0 + chunk * 16;
            u8v v0 = *(u8v*)&Vb[c * 72 + chunk * 16];
            u8v v1 = *(u8v*)&Vb[c * 72 + chunk * 16 + 8];
            *(u8v*)dst = v0; *(u8v*)(dst + 8) = v1;
        }
    } else {
#pragma unroll
        for (int nt = 0; nt < 4; ++nt) {
            int c = n0g + nt * 16 + l15;
            float bv = bias[c];
#pragma unroll
            for (int r = 0; r < 4; ++r) {
                float v = acc[nt][r] + bv;
                v = v > 0.f ? v : 0.f;
                out[(size_t)(m0 + wave * 16 + quad * 4 + r) * Ntot + c] = f2bf(v);
            }
        }
    }
}

// ---- fused tail, 16-WAVE blocks (was 8): same 32-row tile, same LDS, same -
// traffic & math order, but 4 waves/SIMD instead of 2 -> 2x TLP to hide the
// per-step L2 staging latency (the attn R6 lesson applied to the tail).
// Each wave owns a 32-col slice: wr = wave>>3 (row half), wc = wave&7.
__global__ __launch_bounds__(1024, 4) void tail32_k(
    const unsigned short* __restrict__ AO,
    const unsigned short* __restrict__ WoTl, const float* __restrict__ bo,
    const unsigned short* __restrict__ Xres,
    const float* __restrict__ g1, const float* __restrict__ be1,
    const unsigned short* __restrict__ W1Tl, const float* __restrict__ b1,
    const unsigned short* __restrict__ W2Tl, const float* __restrict__ b2,
    const float* __restrict__ g2, const float* __restrict__ be2,
    unsigned short* __restrict__ Xout, float* __restrict__ fout, int last)
{
    __shared__ unsigned short Wt[256 * 72];     // 36864 B
    __shared__ unsigned short As[32 * 72];      //  4608 B
    __shared__ unsigned short X1s[32 * 264];    // 16896 B
    __shared__ unsigned short Hs[32 * 520];     // 33280 B
    __shared__ float LNsc[512];                 //  2048 B   (sum | sumsq at +256)

    const int tid = threadIdx.x;
    const int wave = tid >> 6, lane = tid & 63, l15 = lane & 15, quad = lane >> 4;
    const int wr = wave >> 3, wc = wave & 7;
    const int m0 = blockIdx.x * 32;
    const int rbase = wr * 16 + quad * 4;

    const int wrow = tid >> 2, wcol = (tid & 3) * 16;   // W: 256 rows x 64K, 32B/thread
    const int arow = tid >> 3, acol = (tid & 7) * 8;    // A: 32 rows x 64K (tid<256)

    f4v acc[2];
    u8v w0, w1, a0 = {0,0,0,0,0,0,0,0};

    const unsigned short* wgo = WoTl + (size_t)wrow * 256 + wcol;
    const unsigned short* wg1 = W1Tl + (size_t)wrow * 256 + wcol;
    const unsigned short* wg1b = W1Tl + (size_t)(256 + wrow) * 256 + wcol;
    const unsigned short* wg2 = W2Tl + (size_t)wrow * 512 + wcol;
    const unsigned short* ag  = AO + (size_t)(m0 + arow) * 256 + acol;

#define LDW(p, o) { w0 = *(const u8v*)((p)+(o)); w1 = *(const u8v*)((p)+(o)+8); }
#define STW { *(u8v*)&Wt[wrow*72+wcol] = w0; *(u8v*)&Wt[wrow*72+wcol+8] = w1; }

    // ================= U1: AO @ WoT^T =================
#pragma unroll
    for (int i = 0; i < 2; ++i) acc[i] = (f4v){0.f, 0.f, 0.f, 0.f};
    LDW(wgo, 0);
    if (tid < 256) a0 = *(const u8v*)ag;
    for (int kk = 0; kk < 4; ++kk) {
        STW;
        if (tid < 256) *(u8v*)&As[arow * 72 + acol] = a0;
        __syncthreads();
        if (kk < 3) {
            LDW(wgo, (kk + 1) * 64);
            if (tid < 256) a0 = *(const u8v*)(ag + (kk + 1) * 64);
        } else {
            LDW(wg1, 0);
        }
#pragma unroll
        for (int ks = 0; ks < 2; ++ks) {
            s8v aF = *(const s8v*)&As[(wr * 16 + l15) * 72 + ks * 32 + quad * 8];
#pragma unroll
            for (int nt = 0; nt < 2; ++nt) {
                s8v wF = *(const s8v*)&Wt[(wc * 32 + nt * 16 + l15) * 72 + ks * 32 + quad * 8];
                acc[nt] = __builtin_amdgcn_mfma_f32_16x16x32_bf16(aF, wF, acc[nt], 0, 0, 0);
            }
        }
        __syncthreads();
    }
    // ---- epilogue U1: bias + resid(global X) + LN1 -> X1s ----
    {
        float ps[4] = {0,0,0,0}, pq[4] = {0,0,0,0};
#pragma unroll
        for (int nt = 0; nt < 2; ++nt) {
            int c = wc * 32 + nt * 16 + l15;
            float bv = bo[c];
#pragma unroll
            for (int r = 0; r < 4; ++r) {
                float v = acc[nt][r] + bv + bf2f(Xres[(size_t)(m0 + rbase + r) * D_ + c]);
                acc[nt][r] = v; ps[r] += v; pq[r] += v * v;
            }
        }
#pragma unroll
        for (int r = 0; r < 4; ++r) {
            float s = ps[r], q = pq[r];
            s += __shfl_xor(s, 1); q += __shfl_xor(q, 1);
            s += __shfl_xor(s, 2); q += __shfl_xor(q, 2);
            s += __shfl_xor(s, 4); q += __shfl_xor(q, 4);
            s += __shfl_xor(s, 8); q += __shfl_xor(q, 8);
            if (l15 == 0) { LNsc[(rbase + r) * 8 + wc] = s; LNsc[256 + (rbase + r) * 8 + wc] = q; }
        }
        __syncthreads();
#pragma unroll
        for (int r = 0; r < 4; ++r) {
            int row = rbase + r;
            float s = 0.f, q = 0.f;
#pragma unroll
            for (int j = 0; j < 8; ++j) { s += LNsc[row * 8 + j]; q += LNsc[256 + row * 8 + j]; }
            float m = s * (1.f / 256.f);
            float rs = rsqrtf(q * (1.f / 256.f) - m * m + 1e-5f);
#pragma unroll
            for (int nt = 0; nt < 2; ++nt) {
                int c = wc * 32 + nt * 16 + l15;
                X1s[row * 264 + c] = f2bf((acc[nt][r] - m) * rs * g1[c] + be1[c]);
            }
        }
        __syncthreads();
    }

    // ================= FF1-a: H[:,0:256] = relu(X1 @ W1T[0:256]^T + b1) =====
#pragma unroll
    for (int i = 0; i < 2; ++i) acc[i] = (f4v){0.f, 0.f, 0.f, 0.f};
    for (int kk = 0; kk < 4; ++kk) {
        STW;
        __syncthreads();
        if (kk < 3) LDW(wg1, (kk + 1) * 64) else LDW(wg1b, 0);
#pragma unroll
        for (int ks = 0; ks < 2; ++ks) {
            s8v aF = *(const s8v*)&X1s[(wr * 16 + l15) * 264 + kk * 64 + ks * 32 + quad * 8];
#pragma unroll
            for (int nt = 0; nt < 2; ++nt) {
                s8v wF = *(const s8v*)&Wt[(wc * 32 + nt * 16 + l15) * 72 + ks * 32 + quad * 8];
                acc[nt] = __builtin_amdgcn_mfma_f32_16x16x32_bf16(aF, wF, acc[nt], 0, 0, 0);
            }
        }
        __syncthreads();
    }
#pragma unroll
    for (int nt = 0; nt < 2; ++nt) {
        int c = wc * 32 + nt * 16 + l15;
        float bv = b1[c];
#pragma unroll
        for (int r = 0; r < 4; ++r) {
            float v = acc[nt][r] + bv; v = v > 0.f ? v : 0.f;
            Hs[(rbase + r) * 520 + c] = f2bf(v);
        }
    }

    // ================= FF1-b: H[:,256:512] =================
#pragma unroll
    for (int i = 0; i < 2; ++i) acc[i] = (f4v){0.f, 0.f, 0.f, 0.f};
    for (int kk = 0; kk < 4; ++kk) {
        STW;
        __syncthreads();
        if (kk < 3) LDW(wg1b, (kk + 1) * 64) else LDW(wg2, 0);
#pragma unroll
        for (int ks = 0; ks < 2; ++ks) {
            s8v aF = *(const s8v*)&X1s[(wr * 16 + l15) * 264 + kk * 64 + ks * 32 + quad * 8];
#pragma unroll
            for (int nt = 0; nt < 2; ++nt) {
                s8v wF = *(const s8v*)&Wt[(wc * 32 + nt * 16 + l15) * 72 + ks * 32 + quad * 8];
                acc[nt] = __builtin_amdgcn_mfma_f32_16x16x32_bf16(aF, wF, acc[nt], 0, 0, 0);
            }
        }
        __syncthreads();
    }
#pragma unroll
    for (int nt = 0; nt < 2; ++nt) {
        int c = wc * 32 + nt * 16 + l15;
        float bv = b1[256 + c];
#pragma unroll
        for (int r = 0; r < 4; ++r) {
            float v = acc[nt][r] + bv; v = v > 0.f ? v : 0.f;
            Hs[(rbase + r) * 520 + 256 + c] = f2bf(v);
        }
    }

    // ================= U2: H @ W2T^T =================
#pragma unroll
    for (int i = 0; i < 2; ++i) acc[i] = (f4v){0.f, 0.f, 0.f, 0.f};
    for (int kk = 0; kk < 8; ++kk) {
        STW;
        __syncthreads();                        // also publishes Hs on kk==0
        if (kk < 7) LDW(wg2, (kk + 1) * 64);
#pragma unroll
        for (int ks = 0; ks < 2; ++ks) {
            s8v aF = *(const s8v*)&Hs[(wr * 16 + l15) * 520 + kk * 64 + ks * 32 + quad * 8];
#pragma unroll
            for (int nt = 0; nt < 2; ++nt) {
                s8v wF = *(const s8v*)&Wt[(wc * 32 + nt * 16 + l15) * 72 + ks * 32 + quad * 8];
                acc[nt] = __builtin_amdgcn_mfma_f32_16x16x32_bf16(aF, wF, acc[nt], 0, 0, 0);
            }
        }
        __syncthreads();
    }
    // ---- epilogue U2: bias + resid(X1s) + LN2 -> Xout / f32 out ----
    {
        float ps[4] = {0,0,0,0}, pq[4] = {0,0,0,0};
#pragma unroll
        for (int nt = 0; nt < 2; ++nt) {
            int c = wc * 32 + nt * 16 + l15;
            float bv = b2[c];
#pragma unroll
            for (int r = 0; r < 4; ++r) {
                float v = acc[nt][r] + bv + bf2f(X1s[(rbase + r) * 264 + c]);
                acc[nt][r] = v; ps[r] += v; pq[r] += v * v;
            }
        }
#pragma unroll
        for (int r = 0; r < 4; ++r) {
            float s = ps[r], q = pq[r];
            s += __shfl_xor(s, 1); q += __shfl_xor(q, 1);
            s += __shfl_xor(s, 2); q += __shfl_xor(q, 2);
            s += __shfl_xor(s, 4); q += __shfl_xor(q, 4);
            s += __shfl_xor(s, 8); q += __shfl_xor(q, 8);
            if (l15 == 0) { LNsc[(rbase + r) * 8 + wc] = s; LNsc[256 + (rbase + r) * 8 + wc] = q; }
        }
        __syncthreads();
#pragma unroll
        for (int r = 0; r < 4; ++r) {
            int row = rbase + r;
            float s = 0.f, q = 0.f;
#pragma unroll
            for (int j = 0; j < 8; ++j) { s += LNsc[row * 8 + j]; q += LNsc[256 + row * 8 + j]; }
            float m = s * (1.f / 256.f);
            float rs = rsqrtf(q * (1.f / 256.f) - m * m + 1e-5f);
#pragma unroll
            for (int nt = 0; nt < 2; ++nt) {
                int c = wc * 32 + nt * 16 + l15;
                float val = (acc[nt][r] - m) * rs * g2[c] + be2[c];
                if (!last) {
                    Xout[(size_t)(m0 + row) * D_ + c] = f2bf(val);
                } else {
                    int gr = m0 + row;
                    int t = gr & (T_ - 1), bb = gr >> 11;
                    if (t) fout[((size_t)bb * S_ + t - 1) * D_ + c] = val;
                }
            }
        }
    }
#undef LDW
#undef STW
}

// ---- flash attention, 8-WAVE blocks (R6-proven): group 0 = q-tile x, group 1
// = q-tile 31-x in parallel, shared K/V staging, 16 waves/CU.
#define KTP 5120   // 128*40 u16 per K buffer
#define VTP 4864   // 32*152 u16 per V buffer
__global__ __launch_bounds__(512, 4) void attn_k(
    const unsigned short* __restrict__ Qh, const unsigned short* __restrict__ Kh,
    const unsigned short* __restrict__ VT, unsigned short* __restrict__ AO)
{
    __shared__ unsigned short Kt[2 * KTP];       // [buf][key][dk] pitch 40
    __shared__ unsigned short Vt[2 * VTP];       // [buf][dk][key] pitch 152
    __shared__ unsigned short Ps[8][16 * 136];   // per-wave P [query][key]

    const int tid = threadIdx.x, wave = tid >> 6, lane = tid & 63;
    const int l15 = lane & 15, quad = lane >> 4;
    const int grp = wave >> 2, wl = wave & 3;
    const int bh = blockIdx.y, b = bh >> 3, h = bh & 7;
    const size_t hoff = (size_t)bh * T_ * DK_;
    unsigned short* Pw = &Ps[wave][0];

    const int x = blockIdx.x;                 // 0..15
    const int qt = grp ? 31 - x : x;          // my group's q-tile
    const int nkt = qt / 2 + 1;               // my group's causal k-tiles
    const int nmax = (31 - x) / 2 + 1;        // block-wide k-tiles (grp1 >= grp0)

    const int krow = tid >> 2, kcol = (tid & 3) * 8;
    const int vdk = tid >> 4, vc = (tid & 15) * 8;
    const unsigned short* kgp = Kh + hoff + (size_t)krow * DK_ + kcol;
    const unsigned short* vgp = VT + ((size_t)bh * DK_ + vdk) * T_ + vc;

    u8v kr = *(const u8v*)kgp;
    u8v vr = *(const u8v*)vgp;

    const int q0w = qt * 64 + wl * 16;
    const s8v qB = *(const s8v*)(Qh + hoff + (size_t)(q0w + l15) * DK_ + quad * 8);
    f4v O0 = {0,0,0,0}, O1 = {0,0,0,0};
    float l_i = 0.f;

    for (int kt = 0; kt < nmax; ++kt) {
        unsigned short* Ktb = Kt + (kt & 1) * KTP;
        unsigned short* Vtb = Vt + (kt & 1) * VTP;
        *(u8v*)&Ktb[krow * 40 + kcol] = kr;
        *(u8v*)&Vtb[vdk * 152 + vc]   = vr;
        __syncthreads();
        if (kt + 1 < nmax) {
            kr = *(const u8v*)(kgp + (size_t)(kt + 1) * 128 * DK_);
            vr = *(const u8v*)(vgp + (kt + 1) * 128);
        }
        if (kt < nkt) {
            const int k0 = kt * 128;
            f4v s[8];
            f4v zero = {0,0,0,0};
#pragma unroll
            for (int nt = 0; nt < 8; ++nt) {
                s8v kA = *(const s8v*)&Ktb[(nt * 16 + l15) * 40 + quad * 8];
                s[nt] = __builtin_amdgcn_mfma_f32_16x16x32_bf16(kA, qB, zero, 0, 0, 0);
            }
            if (kt == nkt - 1) {
                int query = q0w + l15;
#pragma unroll
                for (int nt = 0; nt < 8; ++nt)
#pragma unroll
                    for (int r = 0; r < 4; ++r) {
                        int key = k0 + nt * 16 + quad * 4 + r;
                        if (key > query) s[nt][r] = -1e30f;
                    }
            }
            float rs = 0.f;
#pragma unroll
            for (int nt = 0; nt < 8; ++nt)
#pragma unroll
                for (int r = 0; r < 4; ++r) {
                    float p = exp2f(s[nt][r]);   // masked -> exp2(-1e30)=0
                    s[nt][r] = p;
                    rs += p;
                }
            rs += __shfl_xor(rs, 16);
            rs += __shfl_xor(rs, 32);
            l_i += rs;
#pragma unroll
            for (int nt = 0; nt < 8; ++nt) {
                u2v pw;
                pw.x = pack_bf2(s[nt][0], s[nt][1]);
                pw.y = pack_bf2(s[nt][2], s[nt][3]);
                *(u2v*)&Pw[l15 * 136 + nt * 16 + quad * 4] = pw;
            }
#pragma unroll
            for (int ks = 0; ks < 4; ++ks) {
                s8v aP = *(const s8v*)&Pw[l15 * 136 + ks * 32 + quad * 8];
                s8v v0 = *(const s8v*)&Vtb[l15 * 152 + ks * 32 + quad * 8];
                s8v v1 = *(const s8v*)&Vtb[(16 + l15) * 152 + ks * 32 + quad * 8];
                O0 = __builtin_amdgcn_mfma_f32_16x16x32_bf16(aP, v0, O0, 0, 0, 0);
                O1 = __builtin_amdgcn_mfma_f32_16x16x32_bf16(aP, v1, O1, 0, 0, 0);
            }
            if (kt == nkt - 1) {
#pragma unroll
                for (int r = 0; r < 4; ++r) {
                    float linv = 1.f / __shfl(l_i, quad * 4 + r);
                    int row = q0w + quad * 4 + r;
                    size_t base = (size_t)(b * T_ + row) * D_ + h * DK_;
                    AO[base + l15]      = f2bf(O0[r] * linv);
                    AO[base + 16 + l15] = f2bf(O1[r] * linv);
                }
            }
        }
    }
}

extern "C" void kernel_launch(void* const* d_in, const int* in_sizes, int n_in,
                              void* d_out, int out_size, void* d_ws, size_t ws_size,
                              hipStream_t stream)
{
    const float* emb  = (const float*)d_in[0];
    const int*   toks = (const int*)d_in[1];
    const float* tokE = (const float*)d_in[4];
    const float* pe   = (const float*)d_in[5];
    const float* Wq   = (const float*)d_in[6];
    const float* Wk   = (const float*)d_in[7];
    const float* Wv   = (const float*)d_in[8];
    const float* Wo   = (const float*)d_in[9];
    const float* bo   = (const float*)d_in[10];
    const float* g1   = (const float*)d_in[11];
    const float* be1  = (const float*)d_in[12];
    const float* W1   = (const float*)d_in[13];
    const float* b1   = (const float*)d_in[14];
    const float* W2   = (const float*)d_in[15];
    const float* b2   = (const float*)d_in[16];
    const float* g2   = (const float*)d_in[17];
    const float* be2  = (const float*)d_in[18];
    float* out = (float*)d_out;

    unsigned short* ws = (unsigned short*)d_ws;
    size_t off = 0;
    const size_t XSZ = (size_t)B_ * T_ * D_;
    unsigned short* Xa    = ws + off; off += XSZ;
    unsigned short* Xb    = ws + off; off += XSZ;   // unused (layout stability)
    unsigned short* Qh    = ws + off; off += XSZ;
    unsigned short* Kh    = ws + off; off += XSZ;
    unsigned short* VTb   = ws + off; off += XSZ;
    unsigned short* AOb   = ws + off; off += XSZ;
    unsigned short* Hb    = ws + off; off += (size_t)B_ * T_ * DFF_;  // unused
    unsigned short* WqkvT = ws + off; off += (size_t)L_ * 3 * D_ * D_;
    unsigned short* WoT   = ws + off; off += (size_t)L_ * D_ * D_;
    unsigned short* W1T   = ws + off; off += (size_t)L_ * D_ * DFF_;
    unsigned short* W2T   = ws + off; off += (size_t)L_ * DFF_ * D_;
    (void)ws_size; (void)in_sizes; (void)n_in; (void)out_size;
    (void)Xb; (void)Hb;

    prep_k<<<dim3(2048), 256, 0, stream>>>(emb, toks, tokE, pe, Xa,
                                           Wq, Wk, Wv, Wo, W1, W2,
                                           WqkvT, WoT, W1T, W2T);

    for (int l = 0; l < L_; ++l) {
        const unsigned short* wqkv = WqkvT + (size_t)l * 3 * D_ * D_;
        const unsigned short* wo   = WoT + (size_t)l * D_ * D_;
        const unsigned short* w1   = W1T + (size_t)l * D_ * DFF_;
        const unsigned short* w2   = W2T + (size_t)l * DFF_ * D_;
        const int last = (l == L_ - 1);

        gemm64_k<<<dim3(128, 12), 256, 0, stream>>>(Xa, wqkv, nullptr,
                                                    Qh, Kh, VTb, nullptr, D_, D_, 0);
        attn_k<<<dim3(16, 32), 512, 0, stream>>>(Qh, Kh, VTb, AOb);
        tail32_k<<<dim3(256), 1024, 0, stream>>>(AOb, wo, bo + l * D_, Xa,
                                                 g1 + l * D_, be1 + l * D_,
                                                 w1, b1 + l * DFF_,
                                                 w2, b2 + l * D_,
                                                 g2 + l * D_, be2 + l * D_,
                                                 Xa, out, last);
    }
}

// Round 8
// 243.765 us; speedup vs baseline: 1.8650x; 1.0114x over previous
//
#include <hip/hip_runtime.h>
#include <cstdint>
#include <cstddef>

#define B_   4
#define S_   2047
#define T_   2048
#define D_   256
#define H_   8
#define DK_  32
#define DFF_ 512
#define L_   2

typedef short          s8v  __attribute__((ext_vector_type(8)));
typedef float          f4v  __attribute__((ext_vector_type(4)));
typedef unsigned short u8v  __attribute__((ext_vector_type(8)));
typedef unsigned int   u2v  __attribute__((ext_vector_type(2)));
typedef unsigned int   uint32;

union U8 { u8v v; unsigned short e[8]; };

__device__ __forceinline__ float bf2f(unsigned short h) {
    unsigned int u = ((unsigned int)h) << 16;
    float f; __builtin_memcpy(&f, &u, 4); return f;
}
__device__ __forceinline__ unsigned short f2bf(float f) {
    unsigned int u; __builtin_memcpy(&u, &f, 4);
    u += 0x7fffu + ((u >> 16) & 1u);        // RNE
    return (unsigned short)(u >> 16);
}
__device__ __forceinline__ uint32 pack_bf2(float lo, float hi) {
    uint32 a, b;
    __builtin_memcpy(&a, &lo, 4); __builtin_memcpy(&b, &hi, 4);
    a += 0x8000u; b += 0x8000u;
    return __builtin_amdgcn_perm(b, a, 0x07060302);  // hi16(b)<<16 | hi16(a)
}

// log2(e)/sqrt(32): Q pre-scale so softmax runs in base-2 (exp2 = bare v_exp_f32)
#define QSCALE2 0.25503485951542068f

// ------- prep: embed (blocks 0..1023) + ALL weight transposes (1024..2047) --
__global__ __launch_bounds__(256) void prep_k(
    const float* __restrict__ emb, const int* __restrict__ toks,
    const float* __restrict__ tokE, const float* __restrict__ pe,
    unsigned short* __restrict__ X,
    const float* __restrict__ Wq, const float* __restrict__ Wk,
    const float* __restrict__ Wv, const float* __restrict__ Wo,
    const float* __restrict__ W1, const float* __restrict__ W2,
    unsigned short* __restrict__ WqkvT, unsigned short* __restrict__ WoT,
    unsigned short* __restrict__ W1T, unsigned short* __restrict__ W2T)
{
    __shared__ float tile[32][33];
    if (blockIdx.x < 1024) {
        int idx = blockIdx.x * 256 + threadIdx.x;      // B*T*32
        int d8 = (idx & 31) * 8;
        int t  = (idx >> 5) & (T_ - 1);
        int b  = idx >> 16;
        const float* src = (t == 0) ? (emb + b * D_)
                                    : (tokE + (size_t)toks[b * S_ + t - 1] * D_);
        const float* p = pe + (size_t)t * D_ + d8;
        U8 o;
#pragma unroll
        for (int j = 0; j < 8; ++j) o.e[j] = f2bf(src[d8 + j] + p[j]);
        *(u8v*)(X + (size_t)(b * T_ + t) * D_ + d8) = o.v;
        return;
    }
    int idx = blockIdx.x - 1024;
    const float* src; unsigned short* dst; int R, C, tr, tc;
    if (idx < 512) {
        int w = idx >> 7, rem = idx & 127, l = rem >> 6, t = rem & 63;
        tr = t >> 3; tc = t & 7; R = 256; C = 256;
        src = (w == 0 ? Wq : w == 1 ? Wk : w == 2 ? Wv : Wo) + (size_t)l * 65536;
        dst = (w < 3) ? WqkvT + (size_t)l * 196608 + (size_t)w * 65536
                      : WoT + (size_t)l * 65536;
    } else if (idx < 768) {
        int rem = idx - 512, l = rem >> 7, t = rem & 127;
        tr = t >> 4; tc = t & 15; R = 256; C = 512;
        src = W1 + (size_t)l * 131072; dst = W1T + (size_t)l * 131072;
    } else {
        int rem = idx - 768, l = rem >> 7, t = rem & 127;
        tr = t >> 3; tc = t & 7; R = 512; C = 256;
        src = W2 + (size_t)l * 131072; dst = W2T + (size_t)l * 131072;
    }
    int x = threadIdx.x & 31, y = threadIdx.x >> 5;
    int r0 = tr * 32, c0 = tc * 32;
#pragma unroll
    for (int i = 0; i < 32; i += 8) tile[y + i][x] = src[(size_t)(r0 + y + i) * C + c0 + x];
    __syncthreads();
#pragma unroll
    for (int i = 0; i < 32; i += 8)
        dst[(size_t)(c0 + y + i) * R + r0 + x] = f2bf(tile[x][y + i]);
}

// ---- GEMM 64x64 tile, BK=64, reg-prefetch.  C = A[M,K] @ WT[N,K]^T ---------
// mode 0: QKV. blockIdx.y in [0,12): sub=y>>2 (0:Q scaled,1:K,2:V transposed)
__global__ __launch_bounds__(256) void gemm64_k(
    const unsigned short* __restrict__ A, const unsigned short* __restrict__ WT,
    const float* __restrict__ bias,
    unsigned short* __restrict__ oq, unsigned short* __restrict__ ok,
    unsigned short* __restrict__ ov, unsigned short* __restrict__ out,
    int K, int Ntot, int mode)
{
    __shared__ unsigned short At[64 * 72];
    __shared__ unsigned short Wt[64 * 72];
    const int tid = threadIdx.x;
    const int wave = tid >> 6, lane = tid & 63, l15 = lane & 15, quad = lane >> 4;
    const int m0 = blockIdx.x * 64, n0g = blockIdx.y * 64;

    f4v acc[4];
#pragma unroll
    for (int i = 0; i < 4; ++i) acc[i] = (f4v){0.f, 0.f, 0.f, 0.f};

    const int arow = tid >> 2, acg = (tid & 3) * 16;
    const unsigned short* ag = A + (size_t)(m0 + arow) * K + acg;
    const unsigned short* wg = WT + (size_t)(n0g + arow) * K + acg;
    u8v a0 = *(const u8v*)ag, a1 = *(const u8v*)(ag + 8);
    u8v w0 = *(const u8v*)wg, w1 = *(const u8v*)(wg + 8);

    const int niter = K >> 6;
    for (int kk = 0; kk < niter; ++kk) {
        *(u8v*)&At[arow * 72 + acg] = a0; *(u8v*)&At[arow * 72 + acg + 8] = a1;
        *(u8v*)&Wt[arow * 72 + acg] = w0; *(u8v*)&Wt[arow * 72 + acg + 8] = w1;
        __syncthreads();
        if (kk + 1 < niter) {
            int o = (kk + 1) * 64;
            a0 = *(const u8v*)(ag + o); a1 = *(const u8v*)(ag + o + 8);
            w0 = *(const u8v*)(wg + o); w1 = *(const u8v*)(wg + o + 8);
        }
#pragma unroll
        for (int ks = 0; ks < 2; ++ks) {
            s8v aF = *(const s8v*)&At[(wave * 16 + l15) * 72 + ks * 32 + quad * 8];
#pragma unroll
            for (int nt = 0; nt < 4; ++nt) {
                s8v wF = *(const s8v*)&Wt[(nt * 16 + l15) * 72 + ks * 32 + quad * 8];
                acc[nt] = __builtin_amdgcn_mfma_f32_16x16x32_bf16(aF, wF, acc[nt], 0, 0, 0);
            }
        }
        __syncthreads();
    }

    const int b = m0 >> 11, t0 = m0 & (T_ - 1);
    if (mode == 0) {
        int sub = blockIdx.y >> 2;
        int cb  = (blockIdx.y & 3) * 64;
        if (sub < 2) {
            unsigned short* dst = sub ? ok : oq;
            float sc = sub ? 1.f : QSCALE2;
#pragma unroll
            for (int nt = 0; nt < 4; ++nt) {
                int c = cb + nt * 16 + l15, hh = c >> 5, dk = c & 31;
#pragma unroll
                for (int r = 0; r < 4; ++r) {
                    int t = t0 + wave * 16 + quad * 4 + r;
                    dst[((size_t)(b * H_ + hh) * T_ + t) * DK_ + dk] = f2bf(acc[nt][r] * sc);
                }
            }
        } else {
            unsigned short* Vb = At;   // reuse: [64 cols][72]
#pragma unroll
            for (int nt = 0; nt < 4; ++nt) {
                int base = (nt * 16 + l15) * 72 + wave * 16 + quad * 4;
                *(uint32*)&Vb[base]     = pack_bf2(acc[nt][0], acc[nt][1]);
                *(uint32*)&Vb[base + 2] = pack_bf2(acc[nt][2], acc[nt][3]);
            }
            __syncthreads();
            int c = tid >> 2, chunk = tid & 3;
            int cg = cb + c, hh = cg >> 5, dk = cg & 31;
            unsigned short* dst = ov + ((size_t)(b * H_ + hh) * DK_ + dk) * T_ + t0 + chunk * 16;
            u8v v0 = *(u8v*)&Vb[c * 72 + chunk * 16];
            u8v v1 = *(u8v*)&Vb[c * 72 + chunk * 16 + 8];
            *(u8v*)dst = v0; *(u8v*)(dst + 8) = v1;
        }
    } else {
#pragma unroll
        for (int nt = 0; nt < 4; ++nt) {
            int c = n0g + nt * 16 + l15;
            float bv = bias[c];
#pragma unroll
            for (int r = 0; r < 4; ++r) {
                float v = acc[nt][r] + bv;
                v = v > 0.f ? v : 0.f;
                out[(size_t)(m0 + wave * 16 + quad * 4 + r) * Ntot + c] = f2bf(v);
            }
        }
    }
}

// ---- fused tail, 16-WAVE blocks (R7-proven): 4 waves/SIMD to hide per-step
// L2 staging latency.  Each wave owns a 32-col slice.
__global__ __launch_bounds__(1024, 4) void tail32_k(
    const unsigned short* __restrict__ AO,
    const unsigned short* __restrict__ WoTl, const float* __restrict__ bo,
    const unsigned short* __restrict__ Xres,
    const float* __restrict__ g1, const float* __restrict__ be1,
    const unsigned short* __restrict__ W1Tl, const float* __restrict__ b1,
    const unsigned short* __restrict__ W2Tl, const float* __restrict__ b2,
    const float* __restrict__ g2, const float* __restrict__ be2,
    unsigned short* __restrict__ Xout, float* __restrict__ fout, int last)
{
    __shared__ unsigned short Wt[256 * 72];     // 36864 B
    __shared__ unsigned short As[32 * 72];      //  4608 B
    __shared__ unsigned short X1s[32 * 264];    // 16896 B
    __shared__ unsigned short Hs[32 * 520];     // 33280 B
    __shared__ float LNsc[512];                 //  2048 B   (sum | sumsq at +256)

    const int tid = threadIdx.x;
    const int wave = tid >> 6, lane = tid & 63, l15 = lane & 15, quad = lane >> 4;
    const int wr = wave >> 3, wc = wave & 7;
    const int m0 = blockIdx.x * 32;
    const int rbase = wr * 16 + quad * 4;

    const int wrow = tid >> 2, wcol = (tid & 3) * 16;   // W: 256 rows x 64K, 32B/thread
    const int arow = tid >> 3, acol = (tid & 7) * 8;    // A: 32 rows x 64K (tid<256)

    f4v acc[2];
    u8v w0, w1, a0 = {0,0,0,0,0,0,0,0};

    const unsigned short* wgo = WoTl + (size_t)wrow * 256 + wcol;
    const unsigned short* wg1 = W1Tl + (size_t)wrow * 256 + wcol;
    const unsigned short* wg1b = W1Tl + (size_t)(256 + wrow) * 256 + wcol;
    const unsigned short* wg2 = W2Tl + (size_t)wrow * 512 + wcol;
    const unsigned short* ag  = AO + (size_t)(m0 + arow) * 256 + acol;

#define LDW(p, o) { w0 = *(const u8v*)((p)+(o)); w1 = *(const u8v*)((p)+(o)+8); }
#define STW { *(u8v*)&Wt[wrow*72+wcol] = w0; *(u8v*)&Wt[wrow*72+wcol+8] = w1; }

    // ================= U1: AO @ WoT^T =================
#pragma unroll
    for (int i = 0; i < 2; ++i) acc[i] = (f4v){0.f, 0.f, 0.f, 0.f};
    LDW(wgo, 0);
    if (tid < 256) a0 = *(const u8v*)ag;
    for (int kk = 0; kk < 4; ++kk) {
        STW;
        if (tid < 256) *(u8v*)&As[arow * 72 + acol] = a0;
        __syncthreads();
        if (kk < 3) {
            LDW(wgo, (kk + 1) * 64);
            if (tid < 256) a0 = *(const u8v*)(ag + (kk + 1) * 64);
        } else {
            LDW(wg1, 0);
        }
#pragma unroll
        for (int ks = 0; ks < 2; ++ks) {
            s8v aF = *(const s8v*)&As[(wr * 16 + l15) * 72 + ks * 32 + quad * 8];
#pragma unroll
            for (int nt = 0; nt < 2; ++nt) {
                s8v wF = *(const s8v*)&Wt[(wc * 32 + nt * 16 + l15) * 72 + ks * 32 + quad * 8];
                acc[nt] = __builtin_amdgcn_mfma_f32_16x16x32_bf16(aF, wF, acc[nt], 0, 0, 0);
            }
        }
        __syncthreads();
    }
    // ---- epilogue U1: bias + resid(global X) + LN1 -> X1s ----
    {
        float ps[4] = {0,0,0,0}, pq[4] = {0,0,0,0};
#pragma unroll
        for (int nt = 0; nt < 2; ++nt) {
            int c = wc * 32 + nt * 16 + l15;
            float bv = bo[c];
#pragma unroll
            for (int r = 0; r < 4; ++r) {
                float v = acc[nt][r] + bv + bf2f(Xres[(size_t)(m0 + rbase + r) * D_ + c]);
                acc[nt][r] = v; ps[r] += v; pq[r] += v * v;
            }
        }
#pragma unroll
        for (int r = 0; r < 4; ++r) {
            float s = ps[r], q = pq[r];
            s += __shfl_xor(s, 1); q += __shfl_xor(q, 1);
            s += __shfl_xor(s, 2); q += __shfl_xor(q, 2);
            s += __shfl_xor(s, 4); q += __shfl_xor(q, 4);
            s += __shfl_xor(s, 8); q += __shfl_xor(q, 8);
            if (l15 == 0) { LNsc[(rbase + r) * 8 + wc] = s; LNsc[256 + (rbase + r) * 8 + wc] = q; }
        }
        __syncthreads();
#pragma unroll
        for (int r = 0; r < 4; ++r) {
            int row = rbase + r;
            float s = 0.f, q = 0.f;
#pragma unroll
            for (int j = 0; j < 8; ++j) { s += LNsc[row * 8 + j]; q += LNsc[256 + row * 8 + j]; }
            float m = s * (1.f / 256.f);
            float rs = rsqrtf(q * (1.f / 256.f) - m * m + 1e-5f);
#pragma unroll
            for (int nt = 0; nt < 2; ++nt) {
                int c = wc * 32 + nt * 16 + l15;
                X1s[row * 264 + c] = f2bf((acc[nt][r] - m) * rs * g1[c] + be1[c]);
            }
        }
        __syncthreads();
    }

    // ================= FF1-a: H[:,0:256] = relu(X1 @ W1T[0:256]^T + b1) =====
#pragma unroll
    for (int i = 0; i < 2; ++i) acc[i] = (f4v){0.f, 0.f, 0.f, 0.f};
    for (int kk = 0; kk < 4; ++kk) {
        STW;
        __syncthreads();
        if (kk < 3) LDW(wg1, (kk + 1) * 64) else LDW(wg1b, 0);
#pragma unroll
        for (int ks = 0; ks < 2; ++ks) {
            s8v aF = *(const s8v*)&X1s[(wr * 16 + l15) * 264 + kk * 64 + ks * 32 + quad * 8];
#pragma unroll
            for (int nt = 0; nt < 2; ++nt) {
                s8v wF = *(const s8v*)&Wt[(wc * 32 + nt * 16 + l15) * 72 + ks * 32 + quad * 8];
                acc[nt] = __builtin_amdgcn_mfma_f32_16x16x32_bf16(aF, wF, acc[nt], 0, 0, 0);
            }
        }
        __syncthreads();
    }
#pragma unroll
    for (int nt = 0; nt < 2; ++nt) {
        int c = wc * 32 + nt * 16 + l15;
        float bv = b1[c];
#pragma unroll
        for (int r = 0; r < 4; ++r) {
            float v = acc[nt][r] + bv; v = v > 0.f ? v : 0.f;
            Hs[(rbase + r) * 520 + c] = f2bf(v);
        }
    }

    // ================= FF1-b: H[:,256:512] =================
#pragma unroll
    for (int i = 0; i < 2; ++i) acc[i] = (f4v){0.f, 0.f, 0.f, 0.f};
    for (int kk = 0; kk < 4; ++kk) {
        STW;
        __syncthreads();
        if (kk < 3) LDW(wg1b, (kk + 1) * 64) else LDW(wg2, 0);
#pragma unroll
        for (int ks = 0; ks < 2; ++ks) {
            s8v aF = *(const s8v*)&X1s[(wr * 16 + l15) * 264 + kk * 64 + ks * 32 + quad * 8];
#pragma unroll
            for (int nt = 0; nt < 2; ++nt) {
                s8v wF = *(const s8v*)&Wt[(wc * 32 + nt * 16 + l15) * 72 + ks * 32 + quad * 8];
                acc[nt] = __builtin_amdgcn_mfma_f32_16x16x32_bf16(aF, wF, acc[nt], 0, 0, 0);
            }
        }
        __syncthreads();
    }
#pragma unroll
    for (int nt = 0; nt < 2; ++nt) {
        int c = wc * 32 + nt * 16 + l15;
        float bv = b1[256 + c];
#pragma unroll
        for (int r = 0; r < 4; ++r) {
            float v = acc[nt][r] + bv; v = v > 0.f ? v : 0.f;
            Hs[(rbase + r) * 520 + 256 + c] = f2bf(v);
        }
    }

    // ================= U2: H @ W2T^T =================
#pragma unroll
    for (int i = 0; i < 2; ++i) acc[i] = (f4v){0.f, 0.f, 0.f, 0.f};
    for (int kk = 0; kk < 8; ++kk) {
        STW;
        __syncthreads();                        // also publishes Hs on kk==0
        if (kk < 7) LDW(wg2, (kk + 1) * 64);
#pragma unroll
        for (int ks = 0; ks < 2; ++ks) {
            s8v aF = *(const s8v*)&Hs[(wr * 16 + l15) * 520 + kk * 64 + ks * 32 + quad * 8];
#pragma unroll
            for (int nt = 0; nt < 2; ++nt) {
                s8v wF = *(const s8v*)&Wt[(wc * 32 + nt * 16 + l15) * 72 + ks * 32 + quad * 8];
                acc[nt] = __builtin_amdgcn_mfma_f32_16x16x32_bf16(aF, wF, acc[nt], 0, 0, 0);
            }
        }
        __syncthreads();
    }
    // ---- epilogue U2: bias + resid(X1s) + LN2 -> Xout / f32 out ----
    {
        float ps[4] = {0,0,0,0}, pq[4] = {0,0,0,0};
#pragma unroll
        for (int nt = 0; nt < 2; ++nt) {
            int c = wc * 32 + nt * 16 + l15;
            float bv = b2[c];
#pragma unroll
            for (int r = 0; r < 4; ++r) {
                float v = acc[nt][r] + bv + bf2f(X1s[(rbase + r) * 264 + c]);
                acc[nt][r] = v; ps[r] += v; pq[r] += v * v;
            }
        }
#pragma unroll
        for (int r = 0; r < 4; ++r) {
            float s = ps[r], q = pq[r];
            s += __shfl_xor(s, 1); q += __shfl_xor(q, 1);
            s += __shfl_xor(s, 2); q += __shfl_xor(q, 2);
            s += __shfl_xor(s, 4); q += __shfl_xor(q, 4);
            s += __shfl_xor(s, 8); q += __shfl_xor(q, 8);
            if (l15 == 0) { LNsc[(rbase + r) * 8 + wc] = s; LNsc[256 + (rbase + r) * 8 + wc] = q; }
        }
        __syncthreads();
#pragma unroll
        for (int r = 0; r < 4; ++r) {
            int row = rbase + r;
            float s = 0.f, q = 0.f;
#pragma unroll
            for (int j = 0; j < 8; ++j) { s += LNsc[row * 8 + j]; q += LNsc[256 + row * 8 + j]; }
            float m = s * (1.f / 256.f);
            float rs = rsqrtf(q * (1.f / 256.f) - m * m + 1e-5f);
#pragma unroll
            for (int nt = 0; nt < 2; ++nt) {
                int c = wc * 32 + nt * 16 + l15;
                float val = (acc[nt][r] - m) * rs * g2[c] + be2[c];
                if (!last) {
                    Xout[(size_t)(m0 + row) * D_ + c] = f2bf(val);
                } else {
                    int gr = m0 + row;
                    int t = gr & (T_ - 1), bb = gr >> 11;
                    if (t) fout[((size_t)bb * S_ + t - 1) * D_ + c] = val;
                }
            }
        }
    }
#undef LDW
#undef STW
}

// ---- flash attention, 8-wave blocks, CU-LOAD-BALANCED 1D grid.  Same-CU
// block pairs are (bid, bid+256) under the XCD round-robin dispatch model;
// remap makes their x complementary (x, 15-x) so every CU carries the same
// ~25.5 tile-iterations (was: identical x -> 18..32 spread -> 25% drain tail).
#define KTP 5120   // 128*40 u16 per K buffer
#define VTP 4864   // 32*152 u16 per V buffer
__global__ __launch_bounds__(512, 4) void attn_k(
    const unsigned short* __restrict__ Qh, const unsigned short* __restrict__ Kh,
    const unsigned short* __restrict__ VT, unsigned short* __restrict__ AO)
{
    __shared__ unsigned short Kt[2 * KTP];       // [buf][key][dk] pitch 40
    __shared__ unsigned short Vt[2 * VTP];       // [buf][dk][key] pitch 152
    __shared__ unsigned short Ps[8][16 * 136];   // per-wave P [query][key]

    const int tid = threadIdx.x, wave = tid >> 6, lane = tid & 63;
    const int l15 = lane & 15, quad = lane >> 4;
    const int grp = wave >> 2, wl = wave & 3;

    const int bid = blockIdx.x;                  // 0..511
    const int bh = bid >> 4;                     // 0..31
    const int x  = (bid < 256) ? (bid & 15) : 15 - (bid & 15);
    const int b = bh >> 3, h = bh & 7;
    const size_t hoff = (size_t)bh * T_ * DK_;
    unsigned short* Pw = &Ps[wave][0];

    const int qt = grp ? 31 - x : x;          // my group's q-tile
    const int nkt = qt / 2 + 1;               // my group's causal k-tiles
    const int nmax = (31 - x) / 2 + 1;        // block-wide k-tiles (grp1 >= grp0)

    const int krow = tid >> 2, kcol = (tid & 3) * 8;
    const int vdk = tid >> 4, vc = (tid & 15) * 8;
    const unsigned short* kgp = Kh + hoff + (size_t)krow * DK_ + kcol;
    const unsigned short* vgp = VT + ((size_t)bh * DK_ + vdk) * T_ + vc;

    u8v kr = *(const u8v*)kgp;
    u8v vr = *(const u8v*)vgp;

    const int q0w = qt * 64 + wl * 16;
    const s8v qB = *(const s8v*)(Qh + hoff + (size_t)(q0w + l15) * DK_ + quad * 8);
    f4v O0 = {0,0,0,0}, O1 = {0,0,0,0};
    float l_i = 0.f;

    for (int kt = 0; kt < nmax; ++kt) {
        unsigned short* Ktb = Kt + (kt & 1) * KTP;
        unsigned short* Vtb = Vt + (kt & 1) * VTP;
        *(u8v*)&Ktb[krow * 40 + kcol] = kr;
        *(u8v*)&Vtb[vdk * 152 + vc]   = vr;
        __syncthreads();
        if (kt + 1 < nmax) {
            kr = *(const u8v*)(kgp + (size_t)(kt + 1) * 128 * DK_);
            vr = *(const u8v*)(vgp + (kt + 1) * 128);
        }
        if (kt < nkt) {
            const int k0 = kt * 128;
            f4v s[8];
            f4v zero = {0,0,0,0};
#pragma unroll
            for (int nt = 0; nt < 8; ++nt) {
                s8v kA = *(const s8v*)&Ktb[(nt * 16 + l15) * 40 + quad * 8];
                s[nt] = __builtin_amdgcn_mfma_f32_16x16x32_bf16(kA, qB, zero, 0, 0, 0);
            }
            if (kt == nkt - 1) {
                int query = q0w + l15;
#pragma unroll
                for (int nt = 0; nt < 8; ++nt)
#pragma unroll
                    for (int r = 0; r < 4; ++r) {
                        int key = k0 + nt * 16 + quad * 4 + r;
                        if (key > query) s[nt][r] = -1e30f;
                    }
            }
            float rs = 0.f;
#pragma unroll
            for (int nt = 0; nt < 8; ++nt)
#pragma unroll
                for (int r = 0; r < 4; ++r) {
                    float p = exp2f(s[nt][r]);   // masked -> exp2(-1e30)=0
                    s[nt][r] = p;
                    rs += p;
                }
            rs += __shfl_xor(rs, 16);
            rs += __shfl_xor(rs, 32);
            l_i += rs;
#pragma unroll
            for (int nt = 0; nt < 8; ++nt) {
                u2v pw;
                pw.x = pack_bf2(s[nt][0], s[nt][1]);
                pw.y = pack_bf2(s[nt][2], s[nt][3]);
                *(u2v*)&Pw[l15 * 136 + nt * 16 + quad * 4] = pw;
            }
#pragma unroll
            for (int ks = 0; ks < 4; ++ks) {
                s8v aP = *(const s8v*)&Pw[l15 * 136 + ks * 32 + quad * 8];
                s8v v0 = *(const s8v*)&Vtb[l15 * 152 + ks * 32 + quad * 8];
                s8v v1 = *(const s8v*)&Vtb[(16 + l15) * 152 + ks * 32 + quad * 8];
                O0 = __builtin_amdgcn_mfma_f32_16x16x32_bf16(aP, v0, O0, 0, 0, 0);
                O1 = __builtin_amdgcn_mfma_f32_16x16x32_bf16(aP, v1, O1, 0, 0, 0);
            }
            if (kt == nkt - 1) {
#pragma unroll
                for (int r = 0; r < 4; ++r) {
                    float linv = 1.f / __shfl(l_i, quad * 4 + r);
                    int row = q0w + quad * 4 + r;
                    size_t base = (size_t)(b * T_ + row) * D_ + h * DK_;
                    AO[base + l15]      = f2bf(O0[r] * linv);
                    AO[base + 16 + l15] = f2bf(O1[r] * linv);
                }
            }
        }
    }
}

extern "C" void kernel_launch(void* const* d_in, const int* in_sizes, int n_in,
                              void* d_out, int out_size, void* d_ws, size_t ws_size,
                              hipStream_t stream)
{
    const float* emb  = (const float*)d_in[0];
    const int*   toks = (const int*)d_in[1];
    const float* tokE = (const float*)d_in[4];
    const float* pe   = (const float*)d_in[5];
    const float* Wq   = (const float*)d_in[6];
    const float* Wk   = (const float*)d_in[7];
    const float* Wv   = (const float*)d_in[8];
    const float* Wo   = (const float*)d_in[9];
    const float* bo   = (const float*)d_in[10];
    const float* g1   = (const float*)d_in[11];
    const float* be1  = (const float*)d_in[12];
    const float* W1   = (const float*)d_in[13];
    const float* b1   = (const float*)d_in[14];
    const float* W2   = (const float*)d_in[15];
    const float* b2   = (const float*)d_in[16];
    const float* g2   = (const float*)d_in[17];
    const float* be2  = (const float*)d_in[18];
    float* out = (float*)d_out;

    unsigned short* ws = (unsigned short*)d_ws;
    size_t off = 0;
    const size_t XSZ = (size_t)B_ * T_ * D_;
    unsigned short* Xa    = ws + off; off += XSZ;
    unsigned short* Xb    = ws + off; off += XSZ;   // unused (layout stability)
    unsigned short* Qh    = ws + off; off += XSZ;
    unsigned short* Kh    = ws + off; off += XSZ;
    unsigned short* VTb   = ws + off; off += XSZ;
    unsigned short* AOb   = ws + off; off += XSZ;
    unsigned short* Hb    = ws + off; off += (size_t)B_ * T_ * DFF_;  // unused
    unsigned short* WqkvT = ws + off; off += (size_t)L_ * 3 * D_ * D_;
    unsigned short* WoT   = ws + off; off += (size_t)L_ * D_ * D_;
    unsigned short* W1T   = ws + off; off += (size_t)L_ * D_ * DFF_;
    unsigned short* W2T   = ws + off; off += (size_t)L_ * DFF_ * D_;
    (void)ws_size; (void)in_sizes; (void)n_in; (void)out_size;
    (void)Xb; (void)Hb;

    prep_k<<<dim3(2048), 256, 0, stream>>>(emb, toks, tokE, pe, Xa,
                                           Wq, Wk, Wv, Wo, W1, W2,
                                           WqkvT, WoT, W1T, W2T);

    for (int l = 0; l < L_; ++l) {
        const unsigned short* wqkv = WqkvT + (size_t)l * 3 * D_ * D_;
        const unsigned short* wo   = WoT + (size_t)l * D_ * D_;
        const unsigned short* w1   = W1T + (size_t)l * D_ * DFF_;
        const unsigned short* w2   = W2T + (size_t)l * DFF_ * D_;
        const int last = (l == L_ - 1);

        gemm64_k<<<dim3(128, 12), 256, 0, stream>>>(Xa, wqkv, nullptr,
                                                    Qh, Kh, VTb, nullptr, D_, D_, 0);
        attn_k<<<dim3(512), 512, 0, stream>>>(Qh, Kh, VTb, AOb);
        tail32_k<<<dim3(256), 1024, 0, stream>>>(AOb, wo, bo + l * D_, Xa,
                                                 g1 + l * D_, be1 + l * D_,
                                                 w1, b1 + l * DFF_,
                                                 w2, b2 + l * D_,
                                                 g2 + l * D_, be2 + l * D_,
                                                 Xa, out, last);
    }
}